// Round 2
// baseline (1079.357 us; speedup 1.0000x reference)
//
#include <hip/hip_runtime.h>
#include <math.h>

#define Bn 4
#define Cn 256
#define Nn 1024
#define Hn 8
#define Dn 32

// ---------------- K1a: partial sums of da_prior over n-chunks ----------------
__global__ __launch_bounds__(256) void k_prior_part(const float* __restrict__ dap,
                                                    float* __restrict__ pp) {
  int bi = blockIdx.x;            // Bn*32 blocks
  int b = bi >> 5, ch = bi & 31;
  int c = threadIdx.x;
  float s = 0.f;
  int n0 = ch * 32;
  for (int n = n0; n < n0 + 32; ++n) s += dap[(size_t)(b * Nn + n) * Cn + c];
  pp[(size_t)(b * 32 + ch) * Cn + c] = s;
}

// ---------------- K1b: reduce partials -> prior_sum[B,C] ----------------
__global__ __launch_bounds__(256) void k_prior_red(const float* __restrict__ pp,
                                                   float* __restrict__ prior) {
  int i = blockIdx.x * 256 + threadIdx.x;   // Bn*Cn threads
  int b = i >> 8, c = i & 255;
  float s = 0.f;
  for (int ch = 0; ch < 32; ++ch) s += pp[(size_t)(b * 32 + ch) * Cn + c];
  prior[i] = s;
}

// ---------------- T1: transpose node_embeds [B,C,N] -> [B,N,C] ----------------
__global__ __launch_bounds__(256) void k_transpose(const float* __restrict__ ne,
                                                   float* __restrict__ xw) {
  __shared__ float tile[32][33];
  int bi = blockIdx.x;                 // Bn * 8 * 32
  int b = bi >> 8, rem = bi & 255;
  int c0 = (rem >> 5) << 5;            // C/32 = 8 tiles
  int n0 = (rem & 31) << 5;            // N/32 = 32 tiles
  int tx = threadIdx.x & 31, ty = threadIdx.x >> 5;
#pragma unroll
  for (int i = 0; i < 4; ++i) {
    int c = c0 + ty + i * 8;
    tile[ty + i * 8][tx] = ne[(size_t)(b * Cn + c) * Nn + n0 + tx];
  }
  __syncthreads();
#pragma unroll
  for (int i = 0; i < 4; ++i) {
    int n = n0 + ty + i * 8;
    xw[(size_t)(b * Nn + n) * Cn + c0 + tx] = tile[tx][ty + i * 8];
  }
}

// ---------------- K2: prep (diag*x*prior + x) + LayerNorm ----------------
__global__ __launch_bounds__(256) void k_prep_ln(const float* __restrict__ xw,
                                                 const float* __restrict__ eg,
                                                 const float* __restrict__ prior,
                                                 const float* __restrict__ gamma,
                                                 const float* __restrict__ beta,
                                                 float* __restrict__ ln) {
  int bn = blockIdx.x;               // Bn*Nn
  int b = bn >> 10, n = bn & 1023;
  int c = threadIdx.x;
  float x = xw[(size_t)bn * Cn + c];
  float dg = eg[(size_t)(b * Nn + n) * Nn + n];
  float x2 = x * (1.f + dg * prior[b * Cn + c]);
  float s = x2, qq = x2 * x2;
#pragma unroll
  for (int off = 32; off >= 1; off >>= 1) {
    s += __shfl_xor(s, off);
    qq += __shfl_xor(qq, off);
  }
  __shared__ float ss[4], sq[4];
  if ((c & 63) == 0) { ss[c >> 6] = s; sq[c >> 6] = qq; }
  __syncthreads();
  s = ss[0] + ss[1] + ss[2] + ss[3];
  qq = sq[0] + sq[1] + sq[2] + sq[3];
  float mu = s * (1.f / 256.f);
  float var = qq * (1.f / 256.f) - mu * mu;
  float r = rsqrtf(var + 1e-5f);
  ln[(size_t)bn * Cn + c] = (x2 - mu) * r * gamma[c] + beta[c];
}

// ---------------- K3: QKV GEMM [4096,256]@[256,768] -> q,k,v [B,H,N,D] ----------------
__global__ __launch_bounds__(256) void k_qkv_gemm(const float* __restrict__ ln,
                                                  const float* __restrict__ wqkv,
                                                  float* __restrict__ q,
                                                  float* __restrict__ k,
                                                  float* __restrict__ v) {
  __shared__ __align__(16) float at[16][68];   // at[kk][m]
  __shared__ __align__(16) float bt[16][68];   // bt[kk][j]
  int m0 = blockIdx.x * 64;    // 64
  int j0 = blockIdx.y * 64;    // 12
  int t = threadIdx.x;
  int tx = t & 15, ty = t >> 4;
  float4 acc[4] = {};
  for (int k0 = 0; k0 < 256; k0 += 16) {
    {
      int row = t >> 2, k4 = (t & 3) << 2;
      float4 a = *(const float4*)&ln[(size_t)(m0 + row) * 256 + k0 + k4];
      at[k4 + 0][row] = a.x; at[k4 + 1][row] = a.y;
      at[k4 + 2][row] = a.z; at[k4 + 3][row] = a.w;
      int rb = t >> 4, jb = (t & 15) << 2;
      *(float4*)&bt[rb][jb] = *(const float4*)&wqkv[(size_t)(k0 + rb) * 768 + j0 + jb];
    }
    __syncthreads();
#pragma unroll
    for (int kk = 0; kk < 16; ++kk) {
      float4 a4 = *(float4*)&at[kk][ty << 2];
      float4 b4 = *(float4*)&bt[kk][tx << 2];
      acc[0].x += a4.x * b4.x; acc[0].y += a4.x * b4.y; acc[0].z += a4.x * b4.z; acc[0].w += a4.x * b4.w;
      acc[1].x += a4.y * b4.x; acc[1].y += a4.y * b4.y; acc[1].z += a4.y * b4.z; acc[1].w += a4.y * b4.w;
      acc[2].x += a4.z * b4.x; acc[2].y += a4.z * b4.y; acc[2].z += a4.z * b4.z; acc[2].w += a4.z * b4.w;
      acc[3].x += a4.w * b4.x; acc[3].y += a4.w * b4.y; acc[3].z += a4.w * b4.z; acc[3].w += a4.w * b4.w;
    }
    __syncthreads();
  }
  int j = j0 + (tx << 2);
  int three = j >> 8, rem = j & 255, h = rem >> 5, dd = rem & 31;
  float* dst = (three == 0) ? q : ((three == 1) ? k : v);
#pragma unroll
  for (int i = 0; i < 4; ++i) {
    int m = m0 + (ty << 2) + i;
    int bb = m >> 10, n = m & 1023;
    *(float4*)&dst[(size_t)((bb * Hn + h) * Nn + n) * Dn + dd] = acc[i];
  }
}

// ---------------- K4: fused attention + edge accumulation ----------------
// block = 256 threads = 4 waves; wave w handles row n = ng*4+w; all 8 heads looped inside.
__global__ __launch_bounds__(256) void k_attn(const float* __restrict__ qg,
                                              const float* __restrict__ kg_,
                                              const float* __restrict__ vg_,
                                              const float* __restrict__ eg,
                                              const float* __restrict__ w_expand,
                                              const float* __restrict__ b_expand,
                                              const float* __restrict__ w_reduce,
                                              const float* __restrict__ b_reduce,
                                              float* __restrict__ node_tmp,
                                              float* __restrict__ edge_out) {
  __shared__ __align__(16) float q_lds[4 * 256];
  __shared__ __align__(16) float e_lds[4 * 1024];
  __shared__ __align__(16) float k_tile[64 * 32];   // XOR-swizzled float4 slots
  __shared__ __align__(16) float vt_tile[32 * 64];  // transposed v, XOR-swizzled
  __shared__ __align__(16) float a_lds[4 * 64];
  int blk = blockIdx.x;               // Bn * 256
  int b = blk >> 8, ng = blk & 255;
  int t = threadIdx.x, wid = t >> 6, l = t & 63;
  int n_r = ng * 4 + wid;
  {
    int w = t >> 6, hd = (t & 63) * 4;
    int h = hd >> 5, d = hd & 31;
    *(float4*)&q_lds[w * 256 + hd] =
        *(const float4*)&qg[(size_t)((b * Hn + h) * Nn + ng * 4 + w) * Dn + d];
  }
#pragma unroll
  for (int r = 0; r < 4; ++r)
    *(float4*)&e_lds[r * 1024 + t * 4] =
        *(const float4*)&eg[(size_t)(b * Nn + ng * 4 + r) * Nn + t * 4];
  __syncthreads();

  float edge_acc[16];
#pragma unroll
  for (int i = 0; i < 16; ++i) edge_acc[i] = 0.f;
  const float scale = 0.17677669529663687f;   // 1/sqrt(32)
  const float br = b_reduce[0];
  int d = l & 31, mh = l >> 5;

  for (int h = 0; h < Hn; ++h) {
    float4 qreg[8];
#pragma unroll
    for (int jj = 0; jj < 8; ++jj)
      qreg[jj] = *(float4*)&q_lds[wid * 256 + h * 32 + jj * 4];
    float we = w_expand[h], be = b_expand[h], wr = w_reduce[h];
    const float* kg = kg_ + (size_t)((b * Hn + h) * Nn) * Dn;
    const float* vg = vg_ + (size_t)((b * Hn + h) * Nn) * Dn;
    float s[16];
#pragma unroll
    for (int mt = 0; mt < 16; ++mt) {
      {
        int j4 = t & 7;
#pragma unroll
        for (int rr = 0; rr < 2; ++rr) {
          int row = (t >> 3) + rr * 32;
          int slot = j4 ^ (row & 7);
          *(float4*)&k_tile[row * 32 + slot * 4] =
              *(const float4*)&kg[(size_t)(mt * 64 + row) * 32 + j4 * 4];
        }
      }
      __syncthreads();
      float acc = 0.f;
#pragma unroll
      for (int jj = 0; jj < 8; ++jj) {
        float4 kx = *(float4*)&k_tile[l * 32 + ((jj ^ (l & 7)) << 2)];
        acc += qreg[jj].x * kx.x + qreg[jj].y * kx.y + qreg[jj].z * kx.z + qreg[jj].w * kx.w;
      }
      s[mt] = acc * scale + e_lds[wid * 1024 + mt * 64 + l] * we + be;
      __syncthreads();
    }
    // row softmax (wave-wide, 1024 scores: 16 regs/lane)
    float mx = s[0];
#pragma unroll
    for (int i = 1; i < 16; ++i) mx = fmaxf(mx, s[i]);
#pragma unroll
    for (int off = 32; off >= 1; off >>= 1) mx = fmaxf(mx, __shfl_xor(mx, off));
    float p[16];
    float lsum = 0.f;
#pragma unroll
    for (int i = 0; i < 16; ++i) { p[i] = __expf(s[i] - mx); lsum += p[i]; }
#pragma unroll
    for (int off = 32; off >= 1; off >>= 1) lsum += __shfl_xor(lsum, off);
    float inv_l = 1.0f / lsum;
#pragma unroll
    for (int i = 0; i < 16; ++i) edge_acc[i] += wr * (p[i] * inv_l + s[i]);

    // A @ V
    float oacc = 0.f;
#pragma unroll
    for (int mt = 0; mt < 16; ++mt) {
      a_lds[wid * 64 + l] = p[mt] * inv_l;
      {
        int dq = t & 7;
#pragma unroll
        for (int rr = 0; rr < 2; ++rr) {
          int row = (t >> 3) + rr * 32;
          float4 vv = *(const float4*)&vg[(size_t)(mt * 64 + row) * 32 + dq * 4];
          int m4 = row >> 2, mi = row & 3;
#pragma unroll
          for (int i = 0; i < 4; ++i) {
            int dd = dq * 4 + i;
            int slot4 = (m4 & 8) | ((m4 & 7) ^ (dd & 7));
            vt_tile[dd * 64 + slot4 * 4 + mi] = ((const float*)&vv)[i];
          }
        }
      }
      __syncthreads();
#pragma unroll
      for (int j4 = 0; j4 < 8; ++j4) {
        int m4 = mh * 8 + j4;
        float4 a4 = *(float4*)&a_lds[wid * 64 + (m4 << 2)];
        int slot4 = (m4 & 8) | ((m4 & 7) ^ (d & 7));
        float4 v4 = *(float4*)&vt_tile[d * 64 + slot4 * 4];
        oacc += a4.x * v4.x + a4.y * v4.y + a4.z * v4.z + a4.w * v4.w;
      }
      __syncthreads();
    }
    oacc += __shfl_xor(oacc, 32);
    if (l < 32) node_tmp[(size_t)(b * Nn + n_r) * Cn + h * 32 + d] = oacc;
  }
#pragma unroll
  for (int mt = 0; mt < 16; ++mt)
    edge_out[(size_t)(b * Nn + n_r) * Nn + mt * 64 + l] = edge_acc[mt] + br;
}

// ---------------- K5: edge softmax + wsum ----------------
__global__ __launch_bounds__(256) void k_edge_soft(const float* __restrict__ edge,
                                                   float* __restrict__ wsum) {
  int bn = blockIdx.x;      // Bn*Nn
  int t = threadIdx.x;
  const float* row = edge + (size_t)bn * Nn;
  float4 e = *(const float4*)&row[t * 4];
  float mx = fmaxf(fmaxf(e.x, e.y), fmaxf(e.z, e.w));
#pragma unroll
  for (int off = 32; off >= 1; off >>= 1) mx = fmaxf(mx, __shfl_xor(mx, off));
  __shared__ float sm[4], sl[4], sw[4];
  if ((t & 63) == 0) sm[t >> 6] = mx;
  __syncthreads();
  mx = fmaxf(fmaxf(sm[0], sm[1]), fmaxf(sm[2], sm[3]));
  float p0 = __expf(e.x - mx), p1 = __expf(e.y - mx), p2 = __expf(e.z - mx), p3 = __expf(e.w - mx);
  float ls = p0 + p1 + p2 + p3;
  float ws = p0 * e.x + p1 * e.y + p2 * e.z + p3 * e.w;
#pragma unroll
  for (int off = 32; off >= 1; off >>= 1) { ls += __shfl_xor(ls, off); ws += __shfl_xor(ws, off); }
  if ((t & 63) == 0) { sl[t >> 6] = ls; sw[t >> 6] = ws; }
  __syncthreads();
  if (t == 0) {
    float L = sl[0] + sl[1] + sl[2] + sl[3];
    float Wv = sw[0] + sw[1] + sw[2] + sw[3];
    wsum[bn] = Wv / L;
  }
}

// ---------------- K6: (node + wsum*w_fc + b_fc) @ w_proj + b_proj, transposed store ----------------
__global__ __launch_bounds__(256) void k_proj_gemm(const float* __restrict__ nodet,
                                                   const float* __restrict__ wsum,
                                                   const float* __restrict__ wfc,
                                                   const float* __restrict__ bfc,
                                                   const float* __restrict__ wproj,
                                                   const float* __restrict__ bproj,
                                                   float* __restrict__ out) {
  __shared__ __align__(16) float at[16][68];
  __shared__ __align__(16) float bt[16][68];
  __shared__ float ct[64][65];
  int m0 = blockIdx.x * 64;   // 64
  int j0 = blockIdx.y * 64;   // 4
  int t = threadIdx.x;
  int tx = t & 15, ty = t >> 4;
  float4 acc[4] = {};
  for (int k0 = 0; k0 < 256; k0 += 16) {
    {
      int row = t >> 2, k4 = (t & 3) << 2;
      int m = m0 + row;
      float wsm = wsum[m];
      float4 a = *(const float4*)&nodet[(size_t)m * 256 + k0 + k4];
      a.x += wsm * wfc[k0 + k4 + 0] + bfc[k0 + k4 + 0];
      a.y += wsm * wfc[k0 + k4 + 1] + bfc[k0 + k4 + 1];
      a.z += wsm * wfc[k0 + k4 + 2] + bfc[k0 + k4 + 2];
      a.w += wsm * wfc[k0 + k4 + 3] + bfc[k0 + k4 + 3];
      at[k4 + 0][row] = a.x; at[k4 + 1][row] = a.y;
      at[k4 + 2][row] = a.z; at[k4 + 3][row] = a.w;
      int rb = t >> 4, jb = (t & 15) << 2;
      *(float4*)&bt[rb][jb] = *(const float4*)&wproj[(size_t)(k0 + rb) * 256 + j0 + jb];
    }
    __syncthreads();
#pragma unroll
    for (int kk = 0; kk < 16; ++kk) {
      float4 a4 = *(float4*)&at[kk][ty << 2];
      float4 b4 = *(float4*)&bt[kk][tx << 2];
      acc[0].x += a4.x * b4.x; acc[0].y += a4.x * b4.y; acc[0].z += a4.x * b4.z; acc[0].w += a4.x * b4.w;
      acc[1].x += a4.y * b4.x; acc[1].y += a4.y * b4.y; acc[1].z += a4.y * b4.z; acc[1].w += a4.y * b4.w;
      acc[2].x += a4.z * b4.x; acc[2].y += a4.z * b4.y; acc[2].z += a4.z * b4.z; acc[2].w += a4.z * b4.w;
      acc[3].x += a4.w * b4.x; acc[3].y += a4.w * b4.y; acc[3].z += a4.w * b4.z; acc[3].w += a4.w * b4.w;
    }
    __syncthreads();
  }
#pragma unroll
  for (int i = 0; i < 4; ++i) {
    ct[(ty << 2) + i][(tx << 2) + 0] = acc[i].x + bproj[j0 + (tx << 2) + 0];
    ct[(ty << 2) + i][(tx << 2) + 1] = acc[i].y + bproj[j0 + (tx << 2) + 1];
    ct[(ty << 2) + i][(tx << 2) + 2] = acc[i].z + bproj[j0 + (tx << 2) + 2];
    ct[(ty << 2) + i][(tx << 2) + 3] = acc[i].w + bproj[j0 + (tx << 2) + 3];
  }
  __syncthreads();
  int b = m0 >> 10, n0 = m0 & 1023;
  int n4 = t & 15, c0i = t >> 4;
#pragma unroll
  for (int u = 0; u < 4; ++u) {
    int ci = c0i + u * 16;
    float4 val = { ct[(n4 << 2) + 0][ci], ct[(n4 << 2) + 1][ci],
                   ct[(n4 << 2) + 2][ci], ct[(n4 << 2) + 3][ci] };
    *(float4*)&out[(size_t)(b * Cn + j0 + ci) * Nn + n0 + (n4 << 2)] = val;
  }
}

// ---------------- launch ----------------
extern "C" void kernel_launch(void* const* d_in, const int* in_sizes, int n_in,
                              void* d_out, int out_size, void* d_ws, size_t ws_size,
                              hipStream_t stream) {
  (void)in_sizes; (void)n_in; (void)out_size; (void)ws_size;
  const float* node_embeds = (const float*)d_in[0];
  const float* edge_embeds = (const float*)d_in[1];
  const float* da_prior    = (const float*)d_in[2];
  const float* gamma       = (const float*)d_in[3];
  const float* beta        = (const float*)d_in[4];
  const float* w_qkv       = (const float*)d_in[5];
  const float* w_proj      = (const float*)d_in[6];
  const float* b_proj      = (const float*)d_in[7];
  const float* w_expand    = (const float*)d_in[8];
  const float* b_expand    = (const float*)d_in[9];
  const float* w_reduce    = (const float*)d_in[10];
  const float* b_reduce    = (const float*)d_in[11];
  const float* w_fc        = (const float*)d_in[12];
  const float* b_fc        = (const float*)d_in[13];
  float* out_node = (float*)d_out;
  float* out_edge = out_node + (size_t)Bn * Cn * Nn;

  float* W = (float*)d_ws;
  float* ws_x     = W;                    // [B,N,C] x-transposed; reused as node_tmp after K2
  float* ws_ln    = W + 1048576;          // [B,N,C]
  float* ws_q     = W + 2097152;          // [B,H,N,D]
  float* ws_k     = W + 3145728;
  float* ws_v     = W + 4194304;
  float* ws_pp    = W + 5242880;          // [B,32,C]
  float* ws_prior = W + 5275648;          // [B,C]
  float* ws_wsum  = W + 5276672;          // [B,N]

  k_prior_part<<<dim3(Bn * 32), dim3(256), 0, stream>>>(da_prior, ws_pp);
  k_prior_red<<<dim3(Bn), dim3(256), 0, stream>>>(ws_pp, ws_prior);
  k_transpose<<<dim3(Bn * 256), dim3(256), 0, stream>>>(node_embeds, ws_x);
  k_prep_ln<<<dim3(Bn * Nn), dim3(256), 0, stream>>>(ws_x, edge_embeds, ws_prior,
                                                     gamma, beta, ws_ln);
  k_qkv_gemm<<<dim3(64, 12), dim3(256), 0, stream>>>(ws_ln, w_qkv, ws_q, ws_k, ws_v);
  k_attn<<<dim3(Bn * 256), dim3(256), 0, stream>>>(ws_q, ws_k, ws_v, edge_embeds,
                                                   w_expand, b_expand, w_reduce, b_reduce,
                                                   ws_x, out_edge);
  k_edge_soft<<<dim3(Bn * Nn), dim3(256), 0, stream>>>(out_edge, ws_wsum);
  k_proj_gemm<<<dim3(64, 4), dim3(256), 0, stream>>>(ws_x, ws_wsum, w_fc, b_fc,
                                                     w_proj, b_proj, out_node);
}

// Round 3
// 268.190 us; speedup vs baseline: 4.0246x; 4.0246x over previous
//
#include <hip/hip_runtime.h>
#include <math.h>

#define Bn 4
#define Cn 256
#define Nn 1024
#define Hn 8
#define Dn 32

typedef short bf16x8 __attribute__((ext_vector_type(8)));
typedef float f32x4 __attribute__((ext_vector_type(4)));

__device__ inline unsigned f2bf_rn_bits(float x) {
  union { float f; unsigned u; } v; v.f = x;
  return (v.u + 0x7FFFu + ((v.u >> 16) & 1u)) >> 16;
}
__device__ inline float bfbits2f(unsigned b) {
  union { unsigned u; float f; } v; v.u = b << 16; return v.f;
}
__device__ inline void split_bf(float x, unsigned& hi, unsigned& lo) {
  hi = f2bf_rn_bits(x);
  lo = f2bf_rn_bits(x - bfbits2f(hi));
}
// unpack 8 packed u32 (hi | lo<<16) -> hi-plane short8, lo-plane short8
__device__ inline void unpack_u32x8(const uint4& a, const uint4& b, bf16x8& hi, bf16x8& lo) {
  int4 h4, l4;
  h4.x = (int)((a.x & 0xffffu) | (a.y << 16));  l4.x = (int)((a.x >> 16) | (a.y & 0xffff0000u));
  h4.y = (int)((a.z & 0xffffu) | (a.w << 16));  l4.y = (int)((a.z >> 16) | (a.w & 0xffff0000u));
  h4.z = (int)((b.x & 0xffffu) | (b.y << 16));  l4.z = (int)((b.x >> 16) | (b.y & 0xffff0000u));
  h4.w = (int)((b.z & 0xffffu) | (b.w << 16));  l4.w = (int)((b.z >> 16) | (b.w & 0xffff0000u));
  hi = *(bf16x8*)&h4; lo = *(bf16x8*)&l4;
}

// ---------------- K1a: partial sums of da_prior over n-chunks ----------------
__global__ __launch_bounds__(256) void k_prior_part(const float* __restrict__ dap,
                                                    float* __restrict__ pp) {
  int bi = blockIdx.x;
  int b = bi >> 5, ch = bi & 31;
  int c = threadIdx.x;
  float s = 0.f;
  int n0 = ch * 32;
  for (int n = n0; n < n0 + 32; ++n) s += dap[(size_t)(b * Nn + n) * Cn + c];
  pp[(size_t)(b * 32 + ch) * Cn + c] = s;
}

// ---------------- K1b: reduce partials -> prior_sum[B,C] ----------------
__global__ __launch_bounds__(256) void k_prior_red(const float* __restrict__ pp,
                                                   float* __restrict__ prior) {
  int i = blockIdx.x * 256 + threadIdx.x;
  int b = i >> 8, c = i & 255;
  float s = 0.f;
  for (int ch = 0; ch < 32; ++ch) s += pp[(size_t)(b * 32 + ch) * Cn + c];
  prior[i] = s;
}

// ---------------- T1: transpose node_embeds [B,C,N] -> [B,N,C] ----------------
__global__ __launch_bounds__(256) void k_transpose(const float* __restrict__ ne,
                                                   float* __restrict__ xw) {
  __shared__ float tile[32][33];
  int bi = blockIdx.x;
  int b = bi >> 8, rem = bi & 255;
  int c0 = (rem >> 5) << 5;
  int n0 = (rem & 31) << 5;
  int tx = threadIdx.x & 31, ty = threadIdx.x >> 5;
#pragma unroll
  for (int i = 0; i < 4; ++i) {
    int c = c0 + ty + i * 8;
    tile[ty + i * 8][tx] = ne[(size_t)(b * Cn + c) * Nn + n0 + tx];
  }
  __syncthreads();
#pragma unroll
  for (int i = 0; i < 4; ++i) {
    int n = n0 + ty + i * 8;
    xw[(size_t)(b * Nn + n) * Cn + c0 + tx] = tile[tx][ty + i * 8];
  }
}

// ---------------- K2: prep (diag*x*prior + x) + LayerNorm ----------------
__global__ __launch_bounds__(256) void k_prep_ln(const float* __restrict__ xw,
                                                 const float* __restrict__ eg,
                                                 const float* __restrict__ prior,
                                                 const float* __restrict__ gamma,
                                                 const float* __restrict__ beta,
                                                 float* __restrict__ ln) {
  int bn = blockIdx.x;
  int b = bn >> 10, n = bn & 1023;
  int c = threadIdx.x;
  float x = xw[(size_t)bn * Cn + c];
  float dg = eg[(size_t)(b * Nn + n) * Nn + n];
  float x2 = x * (1.f + dg * prior[b * Cn + c]);
  float s = x2, qq = x2 * x2;
#pragma unroll
  for (int off = 32; off >= 1; off >>= 1) {
    s += __shfl_xor(s, off);
    qq += __shfl_xor(qq, off);
  }
  __shared__ float ss[4], sq[4];
  if ((c & 63) == 0) { ss[c >> 6] = s; sq[c >> 6] = qq; }
  __syncthreads();
  s = ss[0] + ss[1] + ss[2] + ss[3];
  qq = sq[0] + sq[1] + sq[2] + sq[3];
  float mu = s * (1.f / 256.f);
  float var = qq * (1.f / 256.f) - mu * mu;
  float r = rsqrtf(var + 1e-5f);
  ln[(size_t)bn * Cn + c] = (x2 - mu) * r * gamma[c] + beta[c];
}

// ---------------- K3: QKV GEMM [4096,256]@[256,768] -> q,k,v [B,H,N,D] ----------------
__global__ __launch_bounds__(256) void k_qkv_gemm(const float* __restrict__ ln,
                                                  const float* __restrict__ wqkv,
                                                  float* __restrict__ q,
                                                  float* __restrict__ k,
                                                  float* __restrict__ v) {
  __shared__ __align__(16) float at[16][68];
  __shared__ __align__(16) float bt[16][68];
  int m0 = blockIdx.x * 64;
  int j0 = blockIdx.y * 64;
  int t = threadIdx.x;
  int tx = t & 15, ty = t >> 4;
  float4 acc[4] = {};
  for (int k0 = 0; k0 < 256; k0 += 16) {
    {
      int row = t >> 2, k4 = (t & 3) << 2;
      float4 a = *(const float4*)&ln[(size_t)(m0 + row) * 256 + k0 + k4];
      at[k4 + 0][row] = a.x; at[k4 + 1][row] = a.y;
      at[k4 + 2][row] = a.z; at[k4 + 3][row] = a.w;
      int rb = t >> 4, jb = (t & 15) << 2;
      *(float4*)&bt[rb][jb] = *(const float4*)&wqkv[(size_t)(k0 + rb) * 768 + j0 + jb];
    }
    __syncthreads();
#pragma unroll
    for (int kk = 0; kk < 16; ++kk) {
      float4 a4 = *(float4*)&at[kk][ty << 2];
      float4 b4 = *(float4*)&bt[kk][tx << 2];
      acc[0].x += a4.x * b4.x; acc[0].y += a4.x * b4.y; acc[0].z += a4.x * b4.z; acc[0].w += a4.x * b4.w;
      acc[1].x += a4.y * b4.x; acc[1].y += a4.y * b4.y; acc[1].z += a4.y * b4.z; acc[1].w += a4.y * b4.w;
      acc[2].x += a4.z * b4.x; acc[2].y += a4.z * b4.y; acc[2].z += a4.z * b4.z; acc[2].w += a4.z * b4.w;
      acc[3].x += a4.w * b4.x; acc[3].y += a4.w * b4.y; acc[3].z += a4.w * b4.z; acc[3].w += a4.w * b4.w;
    }
    __syncthreads();
  }
  int j = j0 + (tx << 2);
  int three = j >> 8, rem = j & 255, h = rem >> 5, dd = rem & 31;
  float* dst = (three == 0) ? q : ((three == 1) ? k : v);
#pragma unroll
  for (int i = 0; i < 4; ++i) {
    int m = m0 + (ty << 2) + i;
    int bb = m >> 10, n = m & 1023;
    *(float4*)&dst[(size_t)((bb * Hn + h) * Nn + n) * Dn + dd] = acc[i];
  }
}

// ---------------- K4a: MFMA attention core: O = softmax(QK^T+bias) V, + row stats ----
// grid: Bn*Hn*16 blocks (b, h, 64-row n-tile); 4 waves, wave = 16 q-rows.
// fp32 accuracy via bf16 hi/lo split (3 MFMAs per product).
__global__ __launch_bounds__(256) void k_attn_core(
    const float* __restrict__ qg, const float* __restrict__ kg_,
    const float* __restrict__ vg_, const float* __restrict__ eg,
    const float* __restrict__ w_expand, const float* __restrict__ b_expand,
    float* __restrict__ node_tmp, float* __restrict__ stats) {
  __shared__ short kh[64 * 40];          // K hi-plane [m-row][d], pad 40
  __shared__ short kl[64 * 40];          // K lo-plane
  __shared__ unsigned vt[32 * 68];       // V transposed [d][m], packed hi|lo<<16
  __shared__ unsigned pbuf[4][16 * 68];  // per-wave P round-trip [q-row][m], packed

  int blk = blockIdx.x;
  int b = blk >> 7;
  int h = (blk >> 4) & 7;
  int nt = blk & 15;
  int n0 = nt * 64;
  int t = threadIdx.x, wid = t >> 6, l = t & 63;
  int lr = l & 15, lq = l >> 4;

  const float scale = 0.17677669529663687f;
  const float we = w_expand[h], be = b_expand[h];
  const float* kg = kg_ + (size_t)((b * Hn + h) * Nn) * Dn;
  const float* vg = vg_ + (size_t)((b * Hn + h) * Nn) * Dn;

  // Q fragment (A-layout: row=lane&15, k=(lane>>4)*8+j), pre-scaled, hi/lo split
  bf16x8 qhi, qlo;
  {
    const float* qp = qg + (size_t)((b * Hn + h) * Nn + n0 + wid * 16 + lr) * Dn + lq * 8;
    float4 a = *(const float4*)qp;
    float4 c = *(const float4*)(qp + 4);
    float vals[8] = {a.x, a.y, a.z, a.w, c.x, c.y, c.z, c.w};
#pragma unroll
    for (int j = 0; j < 8; ++j) {
      unsigned hb, lb;
      split_bf(vals[j] * scale, hb, lb);
      qhi[j] = (short)hb; qlo[j] = (short)lb;
    }
  }

  f32x4 O0 = {0.f, 0.f, 0.f, 0.f}, O1 = {0.f, 0.f, 0.f, 0.f};
  float rowsum[4] = {0.f, 0.f, 0.f, 0.f};

  for (int ms = 0; ms < 16; ++ms) {
    int m0 = ms * 64;
    __syncthreads();  // protect LDS tiles from previous iteration's readers
    // stage K (bf16 hi/lo planes) and V (transposed, packed u32)
#pragma unroll
    for (int it = 0; it < 2; ++it) {
      int idx = t + it * 256;
      int row = idx >> 3, dq = idx & 7;
      float4 kv = *(const float4*)&kg[(size_t)(m0 + row) * Dn + dq * 4];
      unsigned h0, l0, h1, l1, h2, l2, h3, l3;
      split_bf(kv.x, h0, l0); split_bf(kv.y, h1, l1);
      split_bf(kv.z, h2, l2); split_bf(kv.w, h3, l3);
      short4 sh = {(short)h0, (short)h1, (short)h2, (short)h3};
      short4 sl = {(short)l0, (short)l1, (short)l2, (short)l3};
      *(short4*)&kh[row * 40 + dq * 4] = sh;
      *(short4*)&kl[row * 40 + dq * 4] = sl;
      float4 vv = *(const float4*)&vg[(size_t)(m0 + row) * Dn + dq * 4];
      unsigned vh, vl;
      split_bf(vv.x, vh, vl); vt[(dq * 4 + 0) * 68 + row] = vh | (vl << 16);
      split_bf(vv.y, vh, vl); vt[(dq * 4 + 1) * 68 + row] = vh | (vl << 16);
      split_bf(vv.z, vh, vl); vt[(dq * 4 + 2) * 68 + row] = vh | (vl << 16);
      split_bf(vv.w, vh, vl); vt[(dq * 4 + 3) * 68 + row] = vh | (vl << 16);
    }
    __syncthreads();

    // S = QK^T + bias, e = exp(s), rowsum, stash e (hi/lo packed) for PV
#pragma unroll
    for (int msub = 0; msub < 4; ++msub) {
      int mrow = msub * 16 + lr;
      bf16x8 bh = *(bf16x8*)&kh[mrow * 40 + lq * 8];
      bf16x8 bl = *(bf16x8*)&kl[mrow * 40 + lq * 8];
      f32x4 sacc = {0.f, 0.f, 0.f, 0.f};
      sacc = __builtin_amdgcn_mfma_f32_16x16x32_bf16(qlo, bh, sacc, 0, 0, 0);
      sacc = __builtin_amdgcn_mfma_f32_16x16x32_bf16(qhi, bl, sacc, 0, 0, 0);
      sacc = __builtin_amdgcn_mfma_f32_16x16x32_bf16(qhi, bh, sacc, 0, 0, 0);
#pragma unroll
      for (int reg = 0; reg < 4; ++reg) {
        int n = n0 + wid * 16 + lq * 4 + reg;
        float bias = eg[(size_t)(b * Nn + n) * Nn + m0 + msub * 16 + lr] * we + be;
        float s = sacc[reg] + bias;
        float e = __expf(s);   // scores bounded ~|1|: safe without max-sub
        rowsum[reg] += e;
        unsigned hb, lb;
        split_bf(e, hb, lb);
        pbuf[wid][(lq * 4 + reg) * 68 + msub * 16 + lr] = hb | (lb << 16);
      }
    }

    // O += e @ V  (per-wave private pbuf: no barrier needed, lgkmcnt only)
#pragma unroll
    for (int mw = 0; mw < 2; ++mw) {
      uint4 pa = *(uint4*)&pbuf[wid][lr * 68 + mw * 32 + lq * 8];
      uint4 pb = *(uint4*)&pbuf[wid][lr * 68 + mw * 32 + lq * 8 + 4];
      bf16x8 ahi, alo;
      unpack_u32x8(pa, pb, ahi, alo);
      {
        uint4 va = *(uint4*)&vt[lr * 68 + mw * 32 + lq * 8];
        uint4 vb = *(uint4*)&vt[lr * 68 + mw * 32 + lq * 8 + 4];
        bf16x8 vhi, vlo;
        unpack_u32x8(va, vb, vhi, vlo);
        O0 = __builtin_amdgcn_mfma_f32_16x16x32_bf16(alo, vhi, O0, 0, 0, 0);
        O0 = __builtin_amdgcn_mfma_f32_16x16x32_bf16(ahi, vlo, O0, 0, 0, 0);
        O0 = __builtin_amdgcn_mfma_f32_16x16x32_bf16(ahi, vhi, O0, 0, 0, 0);
      }
      {
        uint4 va = *(uint4*)&vt[(16 + lr) * 68 + mw * 32 + lq * 8];
        uint4 vb = *(uint4*)&vt[(16 + lr) * 68 + mw * 32 + lq * 8 + 4];
        bf16x8 vhi, vlo;
        unpack_u32x8(va, vb, vhi, vlo);
        O1 = __builtin_amdgcn_mfma_f32_16x16x32_bf16(alo, vhi, O1, 0, 0, 0);
        O1 = __builtin_amdgcn_mfma_f32_16x16x32_bf16(ahi, vlo, O1, 0, 0, 0);
        O1 = __builtin_amdgcn_mfma_f32_16x16x32_bf16(ahi, vhi, O1, 0, 0, 0);
      }
    }
  }

  // reduce rowsum across the 16-lane col groups
#pragma unroll
  for (int reg = 0; reg < 4; ++reg) {
#pragma unroll
    for (int off = 1; off < 16; off <<= 1)
      rowsum[reg] += __shfl_xor(rowsum[reg], off);
  }
#pragma unroll
  for (int reg = 0; reg < 4; ++reg) {
    float invl = 1.0f / rowsum[reg];
    int n = n0 + wid * 16 + lq * 4 + reg;
    node_tmp[(size_t)(b * Nn + n) * Cn + h * 32 + lr]      = O0[reg] * invl;
    node_tmp[(size_t)(b * Nn + n) * Cn + h * 32 + 16 + lr] = O1[reg] * invl;
    if (lr == 0) stats[(size_t)(b * Hn + h) * Nn + n] = invl;
  }
}

// ---------------- K4b: edge output: recompute S, edge = sum_h wr*(p+s) + br ------
// grid: Bn*16*8 blocks (b, 64-row n-tile, 128-col m-tile); 4 waves.
__global__ __launch_bounds__(256) void k_edge_mfma(
    const float* __restrict__ qg, const float* __restrict__ kg_,
    const float* __restrict__ eg, const float* __restrict__ stats,
    const float* __restrict__ w_expand, const float* __restrict__ b_expand,
    const float* __restrict__ w_reduce, const float* __restrict__ b_reduce,
    float* __restrict__ edge_out) {
  __shared__ short kh[64 * 40];
  __shared__ short kl[64 * 40];
  int blk = blockIdx.x;
  int b = blk >> 7;
  int nt = (blk >> 3) & 15;
  int mt = blk & 7;
  int n0 = nt * 64, mbase = mt * 128;
  int t = threadIdx.x, wid = t >> 6, l = t & 63;
  int lr = l & 15, lq = l >> 4;
  const float scale = 0.17677669529663687f;
  const float br = b_reduce[0];

  float eacc[2][4][4];
  float ebias[2][4][4];
#pragma unroll
  for (int ms = 0; ms < 2; ++ms)
#pragma unroll
    for (int msub = 0; msub < 4; ++msub)
#pragma unroll
      for (int reg = 0; reg < 4; ++reg) {
        int n = n0 + wid * 16 + lq * 4 + reg;
        int m = mbase + ms * 64 + msub * 16 + lr;
        ebias[ms][msub][reg] = eg[(size_t)(b * Nn + n) * Nn + m];
        eacc[ms][msub][reg] = br;
      }

  for (int h = 0; h < Hn; ++h) {
    const float* kg = kg_ + (size_t)((b * Hn + h) * Nn) * Dn;
    float we = w_expand[h], be = b_expand[h], wr = w_reduce[h];
    bf16x8 qhi, qlo;
    {
      const float* qp = qg + (size_t)((b * Hn + h) * Nn + n0 + wid * 16 + lr) * Dn + lq * 8;
      float4 a = *(const float4*)qp;
      float4 c = *(const float4*)(qp + 4);
      float vals[8] = {a.x, a.y, a.z, a.w, c.x, c.y, c.z, c.w};
#pragma unroll
      for (int j = 0; j < 8; ++j) {
        unsigned hb, lb;
        split_bf(vals[j] * scale, hb, lb);
        qhi[j] = (short)hb; qlo[j] = (short)lb;
      }
    }
    float invl[4];
#pragma unroll
    for (int reg = 0; reg < 4; ++reg)
      invl[reg] = stats[(size_t)(b * Hn + h) * Nn + n0 + wid * 16 + lq * 4 + reg];

    for (int ms = 0; ms < 2; ++ms) {
      int m0 = mbase + ms * 64;
      __syncthreads();
#pragma unroll
      for (int it = 0; it < 2; ++it) {
        int idx = t + it * 256;
        int row = idx >> 3, dq = idx & 7;
        float4 kv = *(const float4*)&kg[(size_t)(m0 + row) * Dn + dq * 4];
        unsigned h0, l0, h1, l1, h2, l2, h3, l3;
        split_bf(kv.x, h0, l0); split_bf(kv.y, h1, l1);
        split_bf(kv.z, h2, l2); split_bf(kv.w, h3, l3);
        short4 sh = {(short)h0, (short)h1, (short)h2, (short)h3};
        short4 sl = {(short)l0, (short)l1, (short)l2, (short)l3};
        *(short4*)&kh[row * 40 + dq * 4] = sh;
        *(short4*)&kl[row * 40 + dq * 4] = sl;
      }
      __syncthreads();
#pragma unroll
      for (int msub = 0; msub < 4; ++msub) {
        int mrow = msub * 16 + lr;
        bf16x8 bh = *(bf16x8*)&kh[mrow * 40 + lq * 8];
        bf16x8 bl = *(bf16x8*)&kl[mrow * 40 + lq * 8];
        f32x4 sacc = {0.f, 0.f, 0.f, 0.f};
        sacc = __builtin_amdgcn_mfma_f32_16x16x32_bf16(qlo, bh, sacc, 0, 0, 0);
        sacc = __builtin_amdgcn_mfma_f32_16x16x32_bf16(qhi, bl, sacc, 0, 0, 0);
        sacc = __builtin_amdgcn_mfma_f32_16x16x32_bf16(qhi, bh, sacc, 0, 0, 0);
#pragma unroll
        for (int reg = 0; reg < 4; ++reg) {
          float s = sacc[reg] + ebias[ms][msub][reg] * we + be;
          float p = __expf(s) * invl[reg];
          eacc[ms][msub][reg] += wr * (p + s);
        }
      }
    }
  }
#pragma unroll
  for (int ms = 0; ms < 2; ++ms)
#pragma unroll
    for (int msub = 0; msub < 4; ++msub)
#pragma unroll
      for (int reg = 0; reg < 4; ++reg) {
        int n = n0 + wid * 16 + lq * 4 + reg;
        int m = mbase + ms * 64 + msub * 16 + lr;
        edge_out[(size_t)(b * Nn + n) * Nn + m] = eacc[ms][msub][reg];
      }
}

// ---------------- K5: edge softmax + wsum ----------------
__global__ __launch_bounds__(256) void k_edge_soft(const float* __restrict__ edge,
                                                   float* __restrict__ wsum) {
  int bn = blockIdx.x;
  int t = threadIdx.x;
  const float* row = edge + (size_t)bn * Nn;
  float4 e = *(const float4*)&row[t * 4];
  float mx = fmaxf(fmaxf(e.x, e.y), fmaxf(e.z, e.w));
#pragma unroll
  for (int off = 32; off >= 1; off >>= 1) mx = fmaxf(mx, __shfl_xor(mx, off));
  __shared__ float sm[4], sl[4], sw[4];
  if ((t & 63) == 0) sm[t >> 6] = mx;
  __syncthreads();
  mx = fmaxf(fmaxf(sm[0], sm[1]), fmaxf(sm[2], sm[3]));
  float p0 = __expf(e.x - mx), p1 = __expf(e.y - mx), p2 = __expf(e.z - mx), p3 = __expf(e.w - mx);
  float ls = p0 + p1 + p2 + p3;
  float ws = p0 * e.x + p1 * e.y + p2 * e.z + p3 * e.w;
#pragma unroll
  for (int off = 32; off >= 1; off >>= 1) { ls += __shfl_xor(ls, off); ws += __shfl_xor(ws, off); }
  if ((t & 63) == 0) { sl[t >> 6] = ls; sw[t >> 6] = ws; }
  __syncthreads();
  if (t == 0) {
    float L = sl[0] + sl[1] + sl[2] + sl[3];
    float Wv = sw[0] + sw[1] + sw[2] + sw[3];
    wsum[bn] = Wv / L;
  }
}

// ---------------- K6: (node + wsum*w_fc + b_fc) @ w_proj + b_proj, transposed store ----
__global__ __launch_bounds__(256) void k_proj_gemm(const float* __restrict__ nodet,
                                                   const float* __restrict__ wsum,
                                                   const float* __restrict__ wfc,
                                                   const float* __restrict__ bfc,
                                                   const float* __restrict__ wproj,
                                                   const float* __restrict__ bproj,
                                                   float* __restrict__ out) {
  __shared__ __align__(16) float at[16][68];
  __shared__ __align__(16) float bt[16][68];
  __shared__ float ct[64][65];
  int m0 = blockIdx.x * 64;
  int j0 = blockIdx.y * 64;
  int t = threadIdx.x;
  int tx = t & 15, ty = t >> 4;
  float4 acc[4] = {};
  for (int k0 = 0; k0 < 256; k0 += 16) {
    {
      int row = t >> 2, k4 = (t & 3) << 2;
      int m = m0 + row;
      float wsm = wsum[m];
      float4 a = *(const float4*)&nodet[(size_t)m * 256 + k0 + k4];
      a.x += wsm * wfc[k0 + k4 + 0] + bfc[k0 + k4 + 0];
      a.y += wsm * wfc[k0 + k4 + 1] + bfc[k0 + k4 + 1];
      a.z += wsm * wfc[k0 + k4 + 2] + bfc[k0 + k4 + 2];
      a.w += wsm * wfc[k0 + k4 + 3] + bfc[k0 + k4 + 3];
      at[k4 + 0][row] = a.x; at[k4 + 1][row] = a.y;
      at[k4 + 2][row] = a.z; at[k4 + 3][row] = a.w;
      int rb = t >> 4, jb = (t & 15) << 2;
      *(float4*)&bt[rb][jb] = *(const float4*)&wproj[(size_t)(k0 + rb) * 256 + j0 + jb];
    }
    __syncthreads();
#pragma unroll
    for (int kk = 0; kk < 16; ++kk) {
      float4 a4 = *(float4*)&at[kk][ty << 2];
      float4 b4 = *(float4*)&bt[kk][tx << 2];
      acc[0].x += a4.x * b4.x; acc[0].y += a4.x * b4.y; acc[0].z += a4.x * b4.z; acc[0].w += a4.x * b4.w;
      acc[1].x += a4.y * b4.x; acc[1].y += a4.y * b4.y; acc[1].z += a4.y * b4.z; acc[1].w += a4.y * b4.w;
      acc[2].x += a4.z * b4.x; acc[2].y += a4.z * b4.y; acc[2].z += a4.z * b4.z; acc[2].w += a4.z * b4.w;
      acc[3].x += a4.w * b4.x; acc[3].y += a4.w * b4.y; acc[3].z += a4.w * b4.z; acc[3].w += a4.w * b4.w;
    }
    __syncthreads();
  }
#pragma unroll
  for (int i = 0; i < 4; ++i) {
    ct[(ty << 2) + i][(tx << 2) + 0] = acc[i].x + bproj[j0 + (tx << 2) + 0];
    ct[(ty << 2) + i][(tx << 2) + 1] = acc[i].y + bproj[j0 + (tx << 2) + 1];
    ct[(ty << 2) + i][(tx << 2) + 2] = acc[i].z + bproj[j0 + (tx << 2) + 2];
    ct[(ty << 2) + i][(tx << 2) + 3] = acc[i].w + bproj[j0 + (tx << 2) + 3];
  }
  __syncthreads();
  int b = m0 >> 10, n0 = m0 & 1023;
  int n4 = t & 15, c0i = t >> 4;
#pragma unroll
  for (int u = 0; u < 4; ++u) {
    int ci = c0i + u * 16;
    float4 val = { ct[(n4 << 2) + 0][ci], ct[(n4 << 2) + 1][ci],
                   ct[(n4 << 2) + 2][ci], ct[(n4 << 2) + 3][ci] };
    *(float4*)&out[(size_t)(b * Cn + j0 + ci) * Nn + n0 + (n4 << 2)] = val;
  }
}

// ---------------- launch ----------------
extern "C" void kernel_launch(void* const* d_in, const int* in_sizes, int n_in,
                              void* d_out, int out_size, void* d_ws, size_t ws_size,
                              hipStream_t stream) {
  (void)in_sizes; (void)n_in; (void)out_size; (void)ws_size;
  const float* node_embeds = (const float*)d_in[0];
  const float* edge_embeds = (const float*)d_in[1];
  const float* da_prior    = (const float*)d_in[2];
  const float* gamma       = (const float*)d_in[3];
  const float* beta        = (const float*)d_in[4];
  const float* w_qkv       = (const float*)d_in[5];
  const float* w_proj      = (const float*)d_in[6];
  const float* b_proj      = (const float*)d_in[7];
  const float* w_expand    = (const float*)d_in[8];
  const float* b_expand    = (const float*)d_in[9];
  const float* w_reduce    = (const float*)d_in[10];
  const float* b_reduce    = (const float*)d_in[11];
  const float* w_fc        = (const float*)d_in[12];
  const float* b_fc        = (const float*)d_in[13];
  float* out_node = (float*)d_out;
  float* out_edge = out_node + (size_t)Bn * Cn * Nn;

  float* W = (float*)d_ws;
  float* ws_x     = W;                    // [B,N,C]; reused as node_tmp
  float* ws_ln    = W + 1048576;          // [B,N,C]
  float* ws_q     = W + 2097152;          // [B,H,N,D]
  float* ws_k     = W + 3145728;
  float* ws_v     = W + 4194304;
  float* ws_pp    = W + 5242880;          // [B,32,C]
  float* ws_prior = W + 5275648;          // [B,C]
  float* ws_wsum  = W + 5276672;          // [B,N]
  float* ws_stats = W + 5280768;          // [B,H,N] inv_l

  k_prior_part<<<dim3(Bn * 32), dim3(256), 0, stream>>>(da_prior, ws_pp);
  k_prior_red<<<dim3(Bn), dim3(256), 0, stream>>>(ws_pp, ws_prior);
  k_transpose<<<dim3(Bn * 256), dim3(256), 0, stream>>>(node_embeds, ws_x);
  k_prep_ln<<<dim3(Bn * Nn), dim3(256), 0, stream>>>(ws_x, edge_embeds, ws_prior,
                                                     gamma, beta, ws_ln);
  k_qkv_gemm<<<dim3(64, 12), dim3(256), 0, stream>>>(ws_ln, w_qkv, ws_q, ws_k, ws_v);
  k_attn_core<<<dim3(Bn * Hn * 16), dim3(256), 0, stream>>>(
      ws_q, ws_k, ws_v, edge_embeds, w_expand, b_expand, ws_x, ws_stats);
  k_edge_mfma<<<dim3(Bn * 16 * 8), dim3(256), 0, stream>>>(
      ws_q, ws_k, edge_embeds, ws_stats, w_expand, b_expand, w_reduce, b_reduce,
      out_edge);
  k_edge_soft<<<dim3(Bn * Nn), dim3(256), 0, stream>>>(out_edge, ws_wsum);
  k_proj_gemm<<<dim3(64, 4), dim3(256), 0, stream>>>(ws_x, ws_wsum, w_fc, b_fc,
                                                     w_proj, b_proj, out_node);
}

// Round 4
// 206.987 us; speedup vs baseline: 5.2146x; 1.2957x over previous
//
#include <hip/hip_runtime.h>
#include <math.h>

#define Bn 4
#define Cn 256
#define Nn 1024
#define Hn 8
#define Dn 32

typedef short bf16x8 __attribute__((ext_vector_type(8)));
typedef float f32x4 __attribute__((ext_vector_type(4)));

__device__ inline unsigned f2bf_rn_bits(float x) {
  union { float f; unsigned u; } v; v.f = x;
  return (v.u + 0x7FFFu + ((v.u >> 16) & 1u)) >> 16;
}
__device__ inline float bfbits2f(unsigned b) {
  union { unsigned u; float f; } v; v.u = b << 16; return v.f;
}
__device__ inline void split_bf(float x, unsigned& hi, unsigned& lo) {
  hi = f2bf_rn_bits(x);
  lo = f2bf_rn_bits(x - bfbits2f(hi));
}
__device__ inline void split4(const float4& a, float sc, short4& hs, short4& ls) {
  unsigned hb, lb;
  split_bf(a.x * sc, hb, lb); hs.x = (short)hb; ls.x = (short)lb;
  split_bf(a.y * sc, hb, lb); hs.y = (short)hb; ls.y = (short)lb;
  split_bf(a.z * sc, hb, lb); hs.z = (short)hb; ls.z = (short)lb;
  split_bf(a.w * sc, hb, lb); hs.w = (short)hb; ls.w = (short)lb;
}
// unpack 8 packed u32 (hi | lo<<16) -> hi-plane short8, lo-plane short8
__device__ inline void unpack_u32x8(const uint4& a, const uint4& b, bf16x8& hi, bf16x8& lo) {
  int4 h4, l4;
  h4.x = (int)((a.x & 0xffffu) | (a.y << 16));  l4.x = (int)((a.x >> 16) | (a.y & 0xffff0000u));
  h4.y = (int)((a.z & 0xffffu) | (a.w << 16));  l4.y = (int)((a.z >> 16) | (a.w & 0xffff0000u));
  h4.z = (int)((b.x & 0xffffu) | (b.y << 16));  l4.z = (int)((b.x >> 16) | (b.y & 0xffff0000u));
  h4.w = (int)((b.z & 0xffffu) | (b.w << 16));  l4.w = (int)((b.z >> 16) | (b.w & 0xffff0000u));
  hi = *(bf16x8*)&h4; lo = *(bf16x8*)&l4;
}

// ---------------- K1a: partial sums of da_prior over n-chunks ----------------
__global__ __launch_bounds__(256) void k_prior_part(const float* __restrict__ dap,
                                                    float* __restrict__ pp) {
  int bi = blockIdx.x;
  int b = bi >> 5, ch = bi & 31;
  int c = threadIdx.x;
  float s = 0.f;
  int n0 = ch * 32;
  for (int n = n0; n < n0 + 32; ++n) s += dap[(size_t)(b * Nn + n) * Cn + c];
  pp[(size_t)(b * 32 + ch) * Cn + c] = s;
}

// ---------------- K1b: reduce partials -> prior_sum[B,C] ----------------
__global__ __launch_bounds__(256) void k_prior_red(const float* __restrict__ pp,
                                                   float* __restrict__ prior) {
  int i = blockIdx.x * 256 + threadIdx.x;
  int b = i >> 8, c = i & 255;
  float s = 0.f;
  for (int ch = 0; ch < 32; ++ch) s += pp[(size_t)(b * 32 + ch) * Cn + c];
  prior[i] = s;
}

// ---------------- T1: transpose node_embeds [B,C,N] -> [B,N,C] ----------------
__global__ __launch_bounds__(256) void k_transpose(const float* __restrict__ ne,
                                                   float* __restrict__ xw) {
  __shared__ float tile[32][33];
  int bi = blockIdx.x;
  int b = bi >> 8, rem = bi & 255;
  int c0 = (rem >> 5) << 5;
  int n0 = (rem & 31) << 5;
  int tx = threadIdx.x & 31, ty = threadIdx.x >> 5;
#pragma unroll
  for (int i = 0; i < 4; ++i) {
    int c = c0 + ty + i * 8;
    tile[ty + i * 8][tx] = ne[(size_t)(b * Cn + c) * Nn + n0 + tx];
  }
  __syncthreads();
#pragma unroll
  for (int i = 0; i < 4; ++i) {
    int n = n0 + ty + i * 8;
    xw[(size_t)(b * Nn + n) * Cn + c0 + tx] = tile[tx][ty + i * 8];
  }
}

// ---------------- K2: prep (diag*x*prior + x) + LayerNorm ----------------
__global__ __launch_bounds__(256) void k_prep_ln(const float* __restrict__ xw,
                                                 const float* __restrict__ eg,
                                                 const float* __restrict__ prior,
                                                 const float* __restrict__ gamma,
                                                 const float* __restrict__ beta,
                                                 float* __restrict__ ln) {
  int bn = blockIdx.x;
  int b = bn >> 10, n = bn & 1023;
  int c = threadIdx.x;
  float x = xw[(size_t)bn * Cn + c];
  float dg = eg[(size_t)(b * Nn + n) * Nn + n];
  float x2 = x * (1.f + dg * prior[b * Cn + c]);
  float s = x2, qq = x2 * x2;
#pragma unroll
  for (int off = 32; off >= 1; off >>= 1) {
    s += __shfl_xor(s, off);
    qq += __shfl_xor(qq, off);
  }
  __shared__ float ss[4], sq[4];
  if ((c & 63) == 0) { ss[c >> 6] = s; sq[c >> 6] = qq; }
  __syncthreads();
  s = ss[0] + ss[1] + ss[2] + ss[3];
  qq = sq[0] + sq[1] + sq[2] + sq[3];
  float mu = s * (1.f / 256.f);
  float var = qq * (1.f / 256.f) - mu * mu;
  float r = rsqrtf(var + 1e-5f);
  ln[(size_t)bn * Cn + c] = (x2 - mu) * r * gamma[c] + beta[c];
}

// ---------------- K3: QKV GEMM; epilogue emits bf16 hi/lo planes for Q,K (K pre-scaled) ----
__global__ __launch_bounds__(256) void k_qkv_gemm(const float* __restrict__ ln,
                                                  const float* __restrict__ wqkv,
                                                  short* __restrict__ q_hi,
                                                  short* __restrict__ q_lo,
                                                  short* __restrict__ k_hi,
                                                  short* __restrict__ k_lo,
                                                  float* __restrict__ v) {
  __shared__ __align__(16) float at[16][68];
  __shared__ __align__(16) float bt[16][68];
  int m0 = blockIdx.x * 64;
  int j0 = blockIdx.y * 64;
  int t = threadIdx.x;
  int tx = t & 15, ty = t >> 4;
  float4 acc[4] = {};
  for (int k0 = 0; k0 < 256; k0 += 16) {
    {
      int row = t >> 2, k4 = (t & 3) << 2;
      float4 a = *(const float4*)&ln[(size_t)(m0 + row) * 256 + k0 + k4];
      at[k4 + 0][row] = a.x; at[k4 + 1][row] = a.y;
      at[k4 + 2][row] = a.z; at[k4 + 3][row] = a.w;
      int rb = t >> 4, jb = (t & 15) << 2;
      *(float4*)&bt[rb][jb] = *(const float4*)&wqkv[(size_t)(k0 + rb) * 768 + j0 + jb];
    }
    __syncthreads();
#pragma unroll
    for (int kk = 0; kk < 16; ++kk) {
      float4 a4 = *(float4*)&at[kk][ty << 2];
      float4 b4 = *(float4*)&bt[kk][tx << 2];
      acc[0].x += a4.x * b4.x; acc[0].y += a4.x * b4.y; acc[0].z += a4.x * b4.z; acc[0].w += a4.x * b4.w;
      acc[1].x += a4.y * b4.x; acc[1].y += a4.y * b4.y; acc[1].z += a4.y * b4.z; acc[1].w += a4.y * b4.w;
      acc[2].x += a4.z * b4.x; acc[2].y += a4.z * b4.y; acc[2].z += a4.z * b4.z; acc[2].w += a4.z * b4.w;
      acc[3].x += a4.w * b4.x; acc[3].y += a4.w * b4.y; acc[3].z += a4.w * b4.z; acc[3].w += a4.w * b4.w;
    }
    __syncthreads();
  }
  int j = j0 + (tx << 2);
  int three = j >> 8, rem = j & 255, h = rem >> 5, dd = rem & 31;  // block-uniform 'three'
  const float scale = 0.17677669529663687f;  // 1/sqrt(32), folded into K planes
#pragma unroll
  for (int i = 0; i < 4; ++i) {
    int m = m0 + (ty << 2) + i;
    int bb = m >> 10, n = m & 1023;
    size_t base = (size_t)((bb * Hn + h) * Nn + n) * Dn + dd;
    if (three == 2) {
      *(float4*)&v[base] = acc[i];
    } else if (three == 0) {
      short4 hs, ls; split4(acc[i], 1.0f, hs, ls);
      *(short4*)&q_hi[base] = hs; *(short4*)&q_lo[base] = ls;
    } else {
      short4 hs, ls; split4(acc[i], scale, hs, ls);
      *(short4*)&k_hi[base] = hs; *(short4*)&k_lo[base] = ls;
    }
  }
}

// ---------------- K3b: V [B,H,N,D] fp32 -> transposed bf16 planes [B,H,D,N] ----------------
__global__ __launch_bounds__(256) void k_vt(const float* __restrict__ v,
                                            short* __restrict__ vt_hi,
                                            short* __restrict__ vt_lo) {
  __shared__ float tl[32][33];
  int blk = blockIdx.x;              // Bn*Hn*32
  int bh = blk >> 5, nt = blk & 31;
  int n0 = nt * 32;
  int t = threadIdx.x;
  int r = t >> 5, cc = t & 31;
#pragma unroll
  for (int i = 0; i < 4; ++i)
    tl[r + i * 8][cc] = v[((size_t)bh * Nn + n0 + r + i * 8) * Dn + cc];
  __syncthreads();
  int d = t >> 3, c4 = (t & 7) * 4;
  short4 hs, ls;
  unsigned hb, lb;
  split_bf(tl[c4 + 0][d], hb, lb); hs.x = (short)hb; ls.x = (short)lb;
  split_bf(tl[c4 + 1][d], hb, lb); hs.y = (short)hb; ls.y = (short)lb;
  split_bf(tl[c4 + 2][d], hb, lb); hs.z = (short)hb; ls.z = (short)lb;
  split_bf(tl[c4 + 3][d], hb, lb); hs.w = (short)hb; ls.w = (short)lb;
  size_t ob = ((size_t)bh * Dn + d) * Nn + n0 + c4;
  *(short4*)&vt_hi[ob] = hs;
  *(short4*)&vt_lo[ob] = ls;
}

// ---------------- K4a: MFMA attention core (m-split x2), unnormalized partials ----------
// grid: Bn*Hn*16*2 (b,h,nt,mh); 4 waves; wave = 16 q-rows; 8 m-iters of 64.
__global__ __launch_bounds__(256, 4) void k_attn_core(
    const short* __restrict__ q_hi, const short* __restrict__ q_lo,
    const short* __restrict__ k_hi, const short* __restrict__ k_lo,
    const short* __restrict__ vt_hi, const short* __restrict__ vt_lo,
    const float* __restrict__ eg,
    const float* __restrict__ w_expand, const float* __restrict__ b_expand,
    float* __restrict__ o_part, float* __restrict__ l_part) {
  __shared__ short kh[64 * 40];          // K hi [m][d] pad 40
  __shared__ short kl[64 * 40];
  __shared__ short vth[32 * 72];         // V^T hi [d][m] pad 72
  __shared__ short vtl[32 * 72];
  __shared__ unsigned pbuf[4][16 * 68];  // per-wave P (hi|lo<<16)

  int blk = blockIdx.x;
  int mh = blk & 1;
  int nt = (blk >> 1) & 15;
  int h = (blk >> 5) & 7;
  int b = blk >> 8;
  int n0 = nt * 64;
  int t = threadIdx.x, wid = t >> 6, l = t & 63;
  int lr = l & 15, lq = l >> 4;

  const float we = w_expand[h], be = b_expand[h];
  size_t bhb = (size_t)(b * Hn + h) * Nn * Dn;
  const short* khg = k_hi + bhb;
  const short* klg = k_lo + bhb;
  const short* vhg = vt_hi + bhb;   // [D][N] layout, same flat size
  const short* vlg = vt_lo + bhb;

  bf16x8 qhi, qlo;
  {
    size_t qoff = bhb + (size_t)(n0 + wid * 16 + lr) * Dn + lq * 8;
    qhi = *(const bf16x8*)&q_hi[qoff];
    qlo = *(const bf16x8*)&q_lo[qoff];
  }

  f32x4 O0 = {0.f, 0.f, 0.f, 0.f}, O1 = {0.f, 0.f, 0.f, 0.f};
  float rowsum[4] = {0.f, 0.f, 0.f, 0.f};
  int nrow = n0 + wid * 16 + lq * 4;     // base n of the 4 acc regs

  for (int ms = 0; ms < 8; ++ms) {
    int m0 = mh * 512 + ms * 64;
    __syncthreads();
    {  // stage K planes: 64 rows x 32 shorts each, 16B/thread per plane
      int row = t >> 2, c = (t & 3) * 8;
      *(uint4*)&kh[row * 40 + c] = *(const uint4*)&khg[(size_t)(m0 + row) * Dn + c];
      *(uint4*)&kl[row * 40 + c] = *(const uint4*)&klg[(size_t)(m0 + row) * Dn + c];
      // stage V^T planes: 32 d-rows x 64 shorts
      int d = t >> 3, cm = (t & 7) * 8;
      *(uint4*)&vth[d * 72 + cm] = *(const uint4*)&vhg[(size_t)d * Nn + m0 + cm];
      *(uint4*)&vtl[d * 72 + cm] = *(const uint4*)&vlg[(size_t)d * Nn + m0 + cm];
    }
    __syncthreads();

    // batch-load the 16 edge-bias scalars early (MLP)
    float eb[4][4];
#pragma unroll
    for (int reg = 0; reg < 4; ++reg) {
      const float* ep = &eg[(size_t)(b * Nn + nrow + reg) * Nn + m0 + lr];
#pragma unroll
      for (int msub = 0; msub < 4; ++msub) eb[msub][reg] = ep[msub * 16];
    }

    // S = QK^T + bias; e = exp(s); stash packed e
#pragma unroll
    for (int msub = 0; msub < 4; ++msub) {
      int mrow = msub * 16 + lr;
      bf16x8 bh8 = *(bf16x8*)&kh[mrow * 40 + lq * 8];
      bf16x8 bl8 = *(bf16x8*)&kl[mrow * 40 + lq * 8];
      f32x4 sacc = {0.f, 0.f, 0.f, 0.f};
      sacc = __builtin_amdgcn_mfma_f32_16x16x32_bf16(qlo, bh8, sacc, 0, 0, 0);
      sacc = __builtin_amdgcn_mfma_f32_16x16x32_bf16(qhi, bl8, sacc, 0, 0, 0);
      sacc = __builtin_amdgcn_mfma_f32_16x16x32_bf16(qhi, bh8, sacc, 0, 0, 0);
#pragma unroll
      for (int reg = 0; reg < 4; ++reg) {
        float s = sacc[reg] + eb[msub][reg] * we + be;
        float e = __expf(s);
        rowsum[reg] += e;
        unsigned hb, lb;
        split_bf(e, hb, lb);
        pbuf[wid][(lq * 4 + reg) * 68 + msub * 16 + lr] = hb | (lb << 16);
      }
    }

    // O += e @ V (pbuf per-wave private)
#pragma unroll
    for (int mw = 0; mw < 2; ++mw) {
      uint4 pa = *(uint4*)&pbuf[wid][lr * 68 + mw * 32 + lq * 8];
      uint4 pb = *(uint4*)&pbuf[wid][lr * 68 + mw * 32 + lq * 8 + 4];
      bf16x8 ahi, alo;
      unpack_u32x8(pa, pb, ahi, alo);
      {
        bf16x8 vh8 = *(bf16x8*)&vth[lr * 72 + mw * 32 + lq * 8];
        bf16x8 vl8 = *(bf16x8*)&vtl[lr * 72 + mw * 32 + lq * 8];
        O0 = __builtin_amdgcn_mfma_f32_16x16x32_bf16(alo, vh8, O0, 0, 0, 0);
        O0 = __builtin_amdgcn_mfma_f32_16x16x32_bf16(ahi, vl8, O0, 0, 0, 0);
        O0 = __builtin_amdgcn_mfma_f32_16x16x32_bf16(ahi, vh8, O0, 0, 0, 0);
      }
      {
        bf16x8 vh8 = *(bf16x8*)&vth[(16 + lr) * 72 + mw * 32 + lq * 8];
        bf16x8 vl8 = *(bf16x8*)&vtl[(16 + lr) * 72 + mw * 32 + lq * 8];
        O1 = __builtin_amdgcn_mfma_f32_16x16x32_bf16(alo, vh8, O1, 0, 0, 0);
        O1 = __builtin_amdgcn_mfma_f32_16x16x32_bf16(ahi, vl8, O1, 0, 0, 0);
        O1 = __builtin_amdgcn_mfma_f32_16x16x32_bf16(ahi, vh8, O1, 0, 0, 0);
      }
    }
  }

#pragma unroll
  for (int reg = 0; reg < 4; ++reg) {
#pragma unroll
    for (int off = 1; off < 16; off <<= 1)
      rowsum[reg] += __shfl_xor(rowsum[reg], off);
  }
  size_t pbase = (size_t)mh * (Bn * Hn * Nn * Dn) + bhb;
#pragma unroll
  for (int reg = 0; reg < 4; ++reg) {
    int n = nrow + reg;
    o_part[pbase + (size_t)n * Dn + lr] = O0[reg];
    o_part[pbase + (size_t)n * Dn + 16 + lr] = O1[reg];
    if (lr == 0)
      l_part[(size_t)mh * (Bn * Hn * Nn) + (size_t)(b * Hn + h) * Nn + n] = rowsum[reg];
  }
}

// ---------------- K4a': combine m-halves, normalize, write node_tmp + stats ----------
__global__ __launch_bounds__(256) void k_attn_fix(const float* __restrict__ o_part,
                                                  const float* __restrict__ l_part,
                                                  float* __restrict__ node_tmp,
                                                  float* __restrict__ stats) {
  const int BHND = Bn * Hn * Nn * Dn;
  const int BHN = Bn * Hn * Nn;
  int i = blockIdx.x * 256 + threadIdx.x;
  int bhn = i >> 5, d = i & 31;
  float la = l_part[bhn], lb = l_part[BHN + bhn];
  float invl = 1.0f / (la + lb);
  float o = (o_part[i] + o_part[BHND + i]) * invl;
  int n = bhn & 1023, h = (bhn >> 10) & 7, b = bhn >> 13;
  node_tmp[(size_t)(b * Nn + n) * Cn + h * 32 + d] = o;
  if (d == 0) stats[bhn] = invl;
}

// ---------------- K4b: edge output: recompute S, edge = sum_h wr*(p+s) + br ------
// grid: Bn*16*16 (b, nt, mt); 4 waves; per block: 64n x 64m, 8 heads looped.
__global__ __launch_bounds__(256, 4) void k_edge_mfma(
    const short* __restrict__ q_hi, const short* __restrict__ q_lo,
    const short* __restrict__ k_hi, const short* __restrict__ k_lo,
    const float* __restrict__ eg, const float* __restrict__ stats,
    const float* __restrict__ w_expand, const float* __restrict__ b_expand,
    const float* __restrict__ w_reduce, const float* __restrict__ b_reduce,
    float* __restrict__ edge_out) {
  __shared__ short kh[64 * 40];
  __shared__ short kl[64 * 40];
  int blk = blockIdx.x;
  int mt = blk & 15;
  int nt = (blk >> 4) & 15;
  int b = blk >> 8;
  int n0 = nt * 64, m0 = mt * 64;
  int t = threadIdx.x, wid = t >> 6, l = t & 63;
  int lr = l & 15, lq = l >> 4;
  const float br = b_reduce[0];
  int nrow = n0 + wid * 16 + lq * 4;

  float eacc[4][4], ebias[4][4];
#pragma unroll
  for (int reg = 0; reg < 4; ++reg) {
    const float* ep = &eg[(size_t)(b * Nn + nrow + reg) * Nn + m0 + lr];
#pragma unroll
    for (int msub = 0; msub < 4; ++msub) {
      ebias[msub][reg] = ep[msub * 16];
      eacc[msub][reg] = br;
    }
  }

  for (int h = 0; h < Hn; ++h) {
    size_t bhb = (size_t)(b * Hn + h) * Nn * Dn;
    float we = w_expand[h], be = b_expand[h], wr = w_reduce[h];
    bf16x8 qhi, qlo;
    {
      size_t qoff = bhb + (size_t)(n0 + wid * 16 + lr) * Dn + lq * 8;
      qhi = *(const bf16x8*)&q_hi[qoff];
      qlo = *(const bf16x8*)&q_lo[qoff];
    }
    float invl[4];
#pragma unroll
    for (int reg = 0; reg < 4; ++reg)
      invl[reg] = stats[(size_t)(b * Hn + h) * Nn + nrow + reg];

    __syncthreads();
    {
      int row = t >> 2, c = (t & 3) * 8;
      *(uint4*)&kh[row * 40 + c] = *(const uint4*)&k_hi[bhb + (size_t)(m0 + row) * Dn + c];
      *(uint4*)&kl[row * 40 + c] = *(const uint4*)&k_lo[bhb + (size_t)(m0 + row) * Dn + c];
    }
    __syncthreads();
#pragma unroll
    for (int msub = 0; msub < 4; ++msub) {
      int mrow = msub * 16 + lr;
      bf16x8 bh8 = *(bf16x8*)&kh[mrow * 40 + lq * 8];
      bf16x8 bl8 = *(bf16x8*)&kl[mrow * 40 + lq * 8];
      f32x4 sacc = {0.f, 0.f, 0.f, 0.f};
      sacc = __builtin_amdgcn_mfma_f32_16x16x32_bf16(qlo, bh8, sacc, 0, 0, 0);
      sacc = __builtin_amdgcn_mfma_f32_16x16x32_bf16(qhi, bl8, sacc, 0, 0, 0);
      sacc = __builtin_amdgcn_mfma_f32_16x16x32_bf16(qhi, bh8, sacc, 0, 0, 0);
#pragma unroll
      for (int reg = 0; reg < 4; ++reg) {
        float s = sacc[reg] + ebias[msub][reg] * we + be;
        float p = __expf(s) * invl[reg];
        eacc[msub][reg] += wr * (p + s);
      }
    }
  }
#pragma unroll
  for (int msub = 0; msub < 4; ++msub)
#pragma unroll
    for (int reg = 0; reg < 4; ++reg)
      edge_out[(size_t)(b * Nn + nrow + reg) * Nn + m0 + msub * 16 + lr] = eacc[msub][reg];
}

// ---------------- K5: edge softmax + wsum ----------------
__global__ __launch_bounds__(256) void k_edge_soft(const float* __restrict__ edge,
                                                   float* __restrict__ wsum) {
  int bn = blockIdx.x;
  int t = threadIdx.x;
  const float* row = edge + (size_t)bn * Nn;
  float4 e = *(const float4*)&row[t * 4];
  float mx = fmaxf(fmaxf(e.x, e.y), fmaxf(e.z, e.w));
#pragma unroll
  for (int off = 32; off >= 1; off >>= 1) mx = fmaxf(mx, __shfl_xor(mx, off));
  __shared__ float sm[4], sl[4], sw[4];
  if ((t & 63) == 0) sm[t >> 6] = mx;
  __syncthreads();
  mx = fmaxf(fmaxf(sm[0], sm[1]), fmaxf(sm[2], sm[3]));
  float p0 = __expf(e.x - mx), p1 = __expf(e.y - mx), p2 = __expf(e.z - mx), p3 = __expf(e.w - mx);
  float ls = p0 + p1 + p2 + p3;
  float ws = p0 * e.x + p1 * e.y + p2 * e.z + p3 * e.w;
#pragma unroll
  for (int off = 32; off >= 1; off >>= 1) { ls += __shfl_xor(ls, off); ws += __shfl_xor(ws, off); }
  if ((t & 63) == 0) { sl[t >> 6] = ls; sw[t >> 6] = ws; }
  __syncthreads();
  if (t == 0) {
    float L = sl[0] + sl[1] + sl[2] + sl[3];
    float Wv = sw[0] + sw[1] + sw[2] + sw[3];
    wsum[bn] = Wv / L;
  }
}

// ---------------- K6: (node + wsum*w_fc + b_fc) @ w_proj + b_proj, transposed store ----
__global__ __launch_bounds__(256) void k_proj_gemm(const float* __restrict__ nodet,
                                                   const float* __restrict__ wsum,
                                                   const float* __restrict__ wfc,
                                                   const float* __restrict__ bfc,
                                                   const float* __restrict__ wproj,
                                                   const float* __restrict__ bproj,
                                                   float* __restrict__ out) {
  __shared__ __align__(16) float at[16][68];
  __shared__ __align__(16) float bt[16][68];
  __shared__ float ct[64][65];
  int m0 = blockIdx.x * 64;
  int j0 = blockIdx.y * 64;
  int t = threadIdx.x;
  int tx = t & 15, ty = t >> 4;
  float4 acc[4] = {};
  for (int k0 = 0; k0 < 256; k0 += 16) {
    {
      int row = t >> 2, k4 = (t & 3) << 2;
      int m = m0 + row;
      float wsm = wsum[m];
      float4 a = *(const float4*)&nodet[(size_t)m * 256 + k0 + k4];
      a.x += wsm * wfc[k0 + k4 + 0] + bfc[k0 + k4 + 0];
      a.y += wsm * wfc[k0 + k4 + 1] + bfc[k0 + k4 + 1];
      a.z += wsm * wfc[k0 + k4 + 2] + bfc[k0 + k4 + 2];
      a.w += wsm * wfc[k0 + k4 + 3] + bfc[k0 + k4 + 3];
      at[k4 + 0][row] = a.x; at[k4 + 1][row] = a.y;
      at[k4 + 2][row] = a.z; at[k4 + 3][row] = a.w;
      int rb = t >> 4, jb = (t & 15) << 2;
      *(float4*)&bt[rb][jb] = *(const float4*)&wproj[(size_t)(k0 + rb) * 256 + j0 + jb];
    }
    __syncthreads();
#pragma unroll
    for (int kk = 0; kk < 16; ++kk) {
      float4 a4 = *(float4*)&at[kk][ty << 2];
      float4 b4 = *(float4*)&bt[kk][tx << 2];
      acc[0].x += a4.x * b4.x; acc[0].y += a4.x * b4.y; acc[0].z += a4.x * b4.z; acc[0].w += a4.x * b4.w;
      acc[1].x += a4.y * b4.x; acc[1].y += a4.y * b4.y; acc[1].z += a4.y * b4.z; acc[1].w += a4.y * b4.w;
      acc[2].x += a4.z * b4.x; acc[2].y += a4.z * b4.y; acc[2].z += a4.z * b4.z; acc[2].w += a4.z * b4.w;
      acc[3].x += a4.w * b4.x; acc[3].y += a4.w * b4.y; acc[3].z += a4.w * b4.z; acc[3].w += a4.w * b4.w;
    }
    __syncthreads();
  }
#pragma unroll
  for (int i = 0; i < 4; ++i) {
    ct[(ty << 2) + i][(tx << 2) + 0] = acc[i].x + bproj[j0 + (tx << 2) + 0];
    ct[(ty << 2) + i][(tx << 2) + 1] = acc[i].y + bproj[j0 + (tx << 2) + 1];
    ct[(ty << 2) + i][(tx << 2) + 2] = acc[i].z + bproj[j0 + (tx << 2) + 2];
    ct[(ty << 2) + i][(tx << 2) + 3] = acc[i].w + bproj[j0 + (tx << 2) + 3];
  }
  __syncthreads();
  int b = m0 >> 10, n0 = m0 & 1023;
  int n4 = t & 15, c0i = t >> 4;
#pragma unroll
  for (int u = 0; u < 4; ++u) {
    int ci = c0i + u * 16;
    float4 val = { ct[(n4 << 2) + 0][ci], ct[(n4 << 2) + 1][ci],
                   ct[(n4 << 2) + 2][ci], ct[(n4 << 2) + 3][ci] };
    *(float4*)&out[(size_t)(b * Cn + j0 + ci) * Nn + n0 + (n4 << 2)] = val;
  }
}

// ---------------- launch ----------------
extern "C" void kernel_launch(void* const* d_in, const int* in_sizes, int n_in,
                              void* d_out, int out_size, void* d_ws, size_t ws_size,
                              hipStream_t stream) {
  (void)in_sizes; (void)n_in; (void)out_size; (void)ws_size;
  const float* node_embeds = (const float*)d_in[0];
  const float* edge_embeds = (const float*)d_in[1];
  const float* da_prior    = (const float*)d_in[2];
  const float* gamma       = (const float*)d_in[3];
  const float* beta        = (const float*)d_in[4];
  const float* w_qkv       = (const float*)d_in[5];
  const float* w_proj      = (const float*)d_in[6];
  const float* b_proj      = (const float*)d_in[7];
  const float* w_expand    = (const float*)d_in[8];
  const float* b_expand    = (const float*)d_in[9];
  const float* w_reduce    = (const float*)d_in[10];
  const float* b_reduce    = (const float*)d_in[11];
  const float* w_fc        = (const float*)d_in[12];
  const float* b_fc        = (const float*)d_in[13];
  float* out_node = (float*)d_out;
  float* out_edge = out_node + (size_t)Bn * Cn * Nn;

  const size_t M = 1048576;  // B*N*C elements
  float* W = (float*)d_ws;
  float* ws_x   = W;               // [B,N,C] node_tmp
  float* ws_ln  = W + M;           // ln; later reused for V^T planes
  float* ws_v   = W + 2 * M;       // V fp32 [B,H,N,D]
  short* q_hi   = (short*)(W + 3 * M);          // 1M shorts each
  short* q_lo   = q_hi + M;
  short* k_hi   = q_hi + 2 * M;
  short* k_lo   = q_hi + 3 * M;                 // ends at W + 5M floats
  float* ws_pp    = W + 5 * M;
  float* ws_prior = ws_pp + Bn * 32 * Cn;
  float* ws_wsum  = ws_prior + Bn * Cn;
  float* ws_stats = ws_wsum + Bn * Nn;          // [B,H,N]
  float* l_part   = ws_stats + Bn * Hn * Nn;    // [2][B,H,N]
  short* vt_hi  = (short*)ws_ln;                // [B,H,D,N] planes overlay ln
  short* vt_lo  = vt_hi + M;
  float* o_part = out_edge;  // [2][B,H,N,D] scratch inside d_out (consumed pre-edge)

  k_prior_part<<<dim3(Bn * 32), dim3(256), 0, stream>>>(da_prior, ws_pp);
  k_prior_red<<<dim3(Bn), dim3(256), 0, stream>>>(ws_pp, ws_prior);
  k_transpose<<<dim3(Bn * 256), dim3(256), 0, stream>>>(node_embeds, ws_x);
  k_prep_ln<<<dim3(Bn * Nn), dim3(256), 0, stream>>>(ws_x, edge_embeds, ws_prior,
                                                     gamma, beta, ws_ln);
  k_qkv_gemm<<<dim3(64, 12), dim3(256), 0, stream>>>(ws_ln, w_qkv, q_hi, q_lo,
                                                     k_hi, k_lo, ws_v);
  k_vt<<<dim3(Bn * Hn * 32), dim3(256), 0, stream>>>(ws_v, vt_hi, vt_lo);
  k_attn_core<<<dim3(Bn * Hn * 16 * 2), dim3(256), 0, stream>>>(
      q_hi, q_lo, k_hi, k_lo, vt_hi, vt_lo, edge_embeds, w_expand, b_expand,
      o_part, l_part);
  k_attn_fix<<<dim3(Bn * Hn * Nn * Dn / 256), dim3(256), 0, stream>>>(
      o_part, l_part, ws_x, ws_stats);
  k_edge_mfma<<<dim3(Bn * 16 * 16), dim3(256), 0, stream>>>(
      q_hi, q_lo, k_hi, k_lo, edge_embeds, ws_stats, w_expand, b_expand,
      w_reduce, b_reduce, out_edge);
  k_edge_soft<<<dim3(Bn * Nn), dim3(256), 0, stream>>>(out_edge, ws_wsum);
  k_proj_gemm<<<dim3(64, 4), dim3(256), 0, stream>>>(ws_x, ws_wsum, w_fc, b_fc,
                                                     w_proj, b_proj, out_node);
}

// Round 5
// 199.992 us; speedup vs baseline: 5.3970x; 1.0350x over previous
//
#include <hip/hip_runtime.h>
#include <math.h>

#define Bn 4
#define Cn 256
#define Nn 1024
#define Hn 8
#define Dn 32
#define BHND (Bn * Hn * Nn * Dn)   // 1048576
#define BHN  (Bn * Hn * Nn)        // 32768

typedef short bf16x8 __attribute__((ext_vector_type(8)));
typedef float f32x4 __attribute__((ext_vector_type(4)));

__device__ inline unsigned f2bf_rn_bits(float x) {
  union { float f; unsigned u; } v; v.f = x;
  return (v.u + 0x7FFFu + ((v.u >> 16) & 1u)) >> 16;
}
__device__ inline float bfbits2f(unsigned b) {
  union { unsigned u; float f; } v; v.u = b << 16; return v.f;
}
__device__ inline void split_bf(float x, unsigned& hi, unsigned& lo) {
  hi = f2bf_rn_bits(x);
  lo = f2bf_rn_bits(x - bfbits2f(hi));
}
// truncation split (cheaper; lo absorbs hi error, ~2^-16 rel)
__device__ inline unsigned split_bf_trunc_pack(float x) {
  union { float f; unsigned u; } v; v.f = x;
  unsigned hi = v.u >> 16;
  union { unsigned u; float f; } hv; hv.u = hi << 16;
  union { float f; unsigned u; } r; r.f = x - hv.f;
  return hi | (r.u & 0xffff0000u);
}
__device__ inline void split4(const float4& a, float sc, short4& hs, short4& ls) {
  unsigned hb, lb;
  split_bf(a.x * sc, hb, lb); hs.x = (short)hb; ls.x = (short)lb;
  split_bf(a.y * sc, hb, lb); hs.y = (short)hb; ls.y = (short)lb;
  split_bf(a.z * sc, hb, lb); hs.z = (short)hb; ls.z = (short)lb;
  split_bf(a.w * sc, hb, lb); hs.w = (short)hb; ls.w = (short)lb;
}
__device__ inline void unpack_u32x8(const uint4& a, const uint4& b, bf16x8& hi, bf16x8& lo) {
  int4 h4, l4;
  h4.x = (int)((a.x & 0xffffu) | (a.y << 16));  l4.x = (int)((a.x >> 16) | (a.y & 0xffff0000u));
  h4.y = (int)((a.z & 0xffffu) | (a.w << 16));  l4.y = (int)((a.z >> 16) | (a.w & 0xffff0000u));
  h4.z = (int)((b.x & 0xffffu) | (b.y << 16));  l4.z = (int)((b.x >> 16) | (b.y & 0xffff0000u));
  h4.w = (int)((b.z & 0xffffu) | (b.w << 16));  l4.w = (int)((b.z >> 16) | (b.w & 0xffff0000u));
  hi = *(bf16x8*)&h4; lo = *(bf16x8*)&l4;
}

// ---------------- K1a: partial sums of da_prior over n-chunks ----------------
__global__ __launch_bounds__(256) void k_prior_part(const float* __restrict__ dap,
                                                    float* __restrict__ pp) {
  int bi = blockIdx.x;
  int b = bi >> 5, ch = bi & 31;
  int c = threadIdx.x;
  float s = 0.f;
  int n0 = ch * 32;
  for (int n = n0; n < n0 + 32; ++n) s += dap[(size_t)(b * Nn + n) * Cn + c];
  pp[(size_t)(b * 32 + ch) * Cn + c] = s;
}

// ---------------- K1b: reduce partials -> prior_sum[B,C] ----------------
__global__ __launch_bounds__(256) void k_prior_red(const float* __restrict__ pp,
                                                   float* __restrict__ prior) {
  int i = blockIdx.x * 256 + threadIdx.x;
  int b = i >> 8, c = i & 255;
  float s = 0.f;
  for (int ch = 0; ch < 32; ++ch) s += pp[(size_t)(b * 32 + ch) * Cn + c];
  prior[i] = s;
}

// ---------------- T1: transpose node_embeds [B,C,N] -> [B,N,C] ----------------
__global__ __launch_bounds__(256) void k_transpose(const float* __restrict__ ne,
                                                   float* __restrict__ xw) {
  __shared__ float tile[32][33];
  int bi = blockIdx.x;
  int b = bi >> 8, rem = bi & 255;
  int c0 = (rem >> 5) << 5;
  int n0 = (rem & 31) << 5;
  int tx = threadIdx.x & 31, ty = threadIdx.x >> 5;
#pragma unroll
  for (int i = 0; i < 4; ++i) {
    int c = c0 + ty + i * 8;
    tile[ty + i * 8][tx] = ne[(size_t)(b * Cn + c) * Nn + n0 + tx];
  }
  __syncthreads();
#pragma unroll
  for (int i = 0; i < 4; ++i) {
    int n = n0 + ty + i * 8;
    xw[(size_t)(b * Nn + n) * Cn + c0 + tx] = tile[tx][ty + i * 8];
  }
}

// ---------------- K2: prep (diag*x*prior + x) + LayerNorm ----------------
__global__ __launch_bounds__(256) void k_prep_ln(const float* __restrict__ xw,
                                                 const float* __restrict__ eg,
                                                 const float* __restrict__ prior,
                                                 const float* __restrict__ gamma,
                                                 const float* __restrict__ beta,
                                                 float* __restrict__ ln) {
  int bn = blockIdx.x;
  int b = bn >> 10, n = bn & 1023;
  int c = threadIdx.x;
  float x = xw[(size_t)bn * Cn + c];
  float dg = eg[(size_t)(b * Nn + n) * Nn + n];
  float x2 = x * (1.f + dg * prior[b * Cn + c]);
  float s = x2, qq = x2 * x2;
#pragma unroll
  for (int off = 32; off >= 1; off >>= 1) {
    s += __shfl_xor(s, off);
    qq += __shfl_xor(qq, off);
  }
  __shared__ float ss[4], sq[4];
  if ((c & 63) == 0) { ss[c >> 6] = s; sq[c >> 6] = qq; }
  __syncthreads();
  s = ss[0] + ss[1] + ss[2] + ss[3];
  qq = sq[0] + sq[1] + sq[2] + sq[3];
  float mu = s * (1.f / 256.f);
  float var = qq * (1.f / 256.f) - mu * mu;
  float r = rsqrtf(var + 1e-5f);
  ln[(size_t)bn * Cn + c] = (x2 - mu) * r * gamma[c] + beta[c];
}

// ---------------- K3: QKV GEMM; epilogue emits Q/K planes and V^T planes ----------------
__global__ __launch_bounds__(256) void k_qkv_gemm(const float* __restrict__ ln,
                                                  const float* __restrict__ wqkv,
                                                  short* __restrict__ q_hi,
                                                  short* __restrict__ q_lo,
                                                  short* __restrict__ k_hi,
                                                  short* __restrict__ k_lo,
                                                  short* __restrict__ vt_hi,
                                                  short* __restrict__ vt_lo) {
  __shared__ __align__(16) float at[16][68];
  __shared__ __align__(16) float bt[16][68];
  __shared__ float ct[64][65];
  int m0 = blockIdx.x * 64;
  int j0 = blockIdx.y * 64;
  int t = threadIdx.x;
  int tx = t & 15, ty = t >> 4;
  float4 acc[4] = {};
  for (int k0 = 0; k0 < 256; k0 += 16) {
    {
      int row = t >> 2, k4 = (t & 3) << 2;
      float4 a = *(const float4*)&ln[(size_t)(m0 + row) * 256 + k0 + k4];
      at[k4 + 0][row] = a.x; at[k4 + 1][row] = a.y;
      at[k4 + 2][row] = a.z; at[k4 + 3][row] = a.w;
      int rb = t >> 4, jb = (t & 15) << 2;
      *(float4*)&bt[rb][jb] = *(const float4*)&wqkv[(size_t)(k0 + rb) * 768 + j0 + jb];
    }
    __syncthreads();
#pragma unroll
    for (int kk = 0; kk < 16; ++kk) {
      float4 a4 = *(float4*)&at[kk][ty << 2];
      float4 b4 = *(float4*)&bt[kk][tx << 2];
      acc[0].x += a4.x * b4.x; acc[0].y += a4.x * b4.y; acc[0].z += a4.x * b4.z; acc[0].w += a4.x * b4.w;
      acc[1].x += a4.y * b4.x; acc[1].y += a4.y * b4.y; acc[1].z += a4.y * b4.z; acc[1].w += a4.y * b4.w;
      acc[2].x += a4.z * b4.x; acc[2].y += a4.z * b4.y; acc[2].z += a4.z * b4.z; acc[2].w += a4.z * b4.w;
      acc[3].x += a4.w * b4.x; acc[3].y += a4.w * b4.y; acc[3].z += a4.w * b4.z; acc[3].w += a4.w * b4.w;
    }
    __syncthreads();
  }
  int b = m0 >> 10, n0 = m0 & 1023;
  int three = (j0 + (tx << 2)) >> 8;   // block-uniform
  const float scale = 0.17677669529663687f;  // 1/sqrt(32), folded into K planes
  if (three == 2) {
    // V block: LDS transpose -> write V^T bf16 planes [B,H,D,N]
#pragma unroll
    for (int i = 0; i < 4; ++i) {
      ct[(ty << 2) + i][(tx << 2) + 0] = acc[i].x;
      ct[(ty << 2) + i][(tx << 2) + 1] = acc[i].y;
      ct[(ty << 2) + i][(tx << 2) + 2] = acc[i].z;
      ct[(ty << 2) + i][(tx << 2) + 3] = acc[i].w;
    }
    __syncthreads();
    int jl = t >> 2;            // local j 0..63
    int n4 = (t & 3) * 16;      // 16 n-values per thread
    int rem = (j0 & 255) + jl;
    int h = rem >> 5, d = rem & 31;
    short hs[16], ls[16];
#pragma unroll
    for (int u = 0; u < 16; ++u) {
      unsigned hb, lb;
      split_bf(ct[n4 + u][jl], hb, lb);
      hs[u] = (short)hb; ls[u] = (short)lb;
    }
    size_t ob = ((size_t)(b * Hn + h) * Dn + d) * Nn + n0 + n4;
    *(uint4*)&vt_hi[ob] = *(uint4*)&hs[0];
    *(uint4*)&vt_hi[ob + 8] = *(uint4*)&hs[8];
    *(uint4*)&vt_lo[ob] = *(uint4*)&ls[0];
    *(uint4*)&vt_lo[ob + 8] = *(uint4*)&ls[8];
  } else {
    int j = j0 + (tx << 2);
    int rem = j & 255, h = rem >> 5, dd = rem & 31;
    short* dst_hi = (three == 0) ? q_hi : k_hi;
    short* dst_lo = (three == 0) ? q_lo : k_lo;
    float sc = (three == 0) ? 1.0f : scale;
#pragma unroll
    for (int i = 0; i < 4; ++i) {
      int m = m0 + (ty << 2) + i;
      int bb = m >> 10, n = m & 1023;
      size_t base = (size_t)((bb * Hn + h) * Nn + n) * Dn + dd;
      short4 hs, ls; split4(acc[i], sc, hs, ls);
      *(short4*)&dst_hi[base] = hs; *(short4*)&dst_lo[base] = ls;
    }
  }
}

// ---------------- K4a: MFMA attention core (m-split x2), unnormalized partials ----------
__global__ __launch_bounds__(256, 4) void k_attn_core(
    const short* __restrict__ q_hi, const short* __restrict__ q_lo,
    const short* __restrict__ k_hi, const short* __restrict__ k_lo,
    const short* __restrict__ vt_hi, const short* __restrict__ vt_lo,
    const float* __restrict__ eg,
    const float* __restrict__ w_expand, const float* __restrict__ b_expand,
    float* __restrict__ o_part, float* __restrict__ l_part) {
  __shared__ short kh[64 * 40];
  __shared__ short kl[64 * 40];
  __shared__ short vth[32 * 72];
  __shared__ short vtl[32 * 72];
  __shared__ unsigned pbuf[4][16 * 68];

  int blk = blockIdx.x;
  int mh = blk & 1;
  int nt = (blk >> 1) & 15;
  int h = (blk >> 5) & 7;
  int b = blk >> 8;
  int n0 = nt * 64;
  int t = threadIdx.x, wid = t >> 6, l = t & 63;
  int lr = l & 15, lq = l >> 4;

  const float we = w_expand[h], be = b_expand[h];
  size_t bhb = (size_t)(b * Hn + h) * Nn * Dn;
  const short* khg = k_hi + bhb;
  const short* klg = k_lo + bhb;
  const short* vhg = vt_hi + bhb;
  const short* vlg = vt_lo + bhb;

  bf16x8 qhi, qlo;
  {
    size_t qoff = bhb + (size_t)(n0 + wid * 16 + lr) * Dn + lq * 8;
    qhi = *(const bf16x8*)&q_hi[qoff];
    qlo = *(const bf16x8*)&q_lo[qoff];
  }

  f32x4 O0 = {0.f, 0.f, 0.f, 0.f}, O1 = {0.f, 0.f, 0.f, 0.f};
  float rowsum[4] = {0.f, 0.f, 0.f, 0.f};
  int nrow = n0 + wid * 16 + lq * 4;

  for (int ms = 0; ms < 8; ++ms) {
    int m0 = mh * 512 + ms * 64;
    // hoist scattered edge-bias loads: issue before barriers so latency
    // overlaps LDS staging (they have no LDS dependence)
    float eb[4][4];
#pragma unroll
    for (int reg = 0; reg < 4; ++reg) {
      const float* ep = &eg[(size_t)(b * Nn + nrow + reg) * Nn + m0 + lr];
#pragma unroll
      for (int msub = 0; msub < 4; ++msub) eb[msub][reg] = ep[msub * 16];
    }
    __syncthreads();
    {
      int row = t >> 2, c = (t & 3) * 8;
      *(uint4*)&kh[row * 40 + c] = *(const uint4*)&khg[(size_t)(m0 + row) * Dn + c];
      *(uint4*)&kl[row * 40 + c] = *(const uint4*)&klg[(size_t)(m0 + row) * Dn + c];
      int d = t >> 3, cm = (t & 7) * 8;
      *(uint4*)&vth[d * 72 + cm] = *(const uint4*)&vhg[(size_t)d * Nn + m0 + cm];
      *(uint4*)&vtl[d * 72 + cm] = *(const uint4*)&vlg[(size_t)d * Nn + m0 + cm];
    }
    __syncthreads();

#pragma unroll
    for (int msub = 0; msub < 4; ++msub) {
      int mrow = msub * 16 + lr;
      bf16x8 bh8 = *(bf16x8*)&kh[mrow * 40 + lq * 8];
      bf16x8 bl8 = *(bf16x8*)&kl[mrow * 40 + lq * 8];
      f32x4 sacc = {0.f, 0.f, 0.f, 0.f};
      sacc = __builtin_amdgcn_mfma_f32_16x16x32_bf16(qlo, bh8, sacc, 0, 0, 0);
      sacc = __builtin_amdgcn_mfma_f32_16x16x32_bf16(qhi, bl8, sacc, 0, 0, 0);
      sacc = __builtin_amdgcn_mfma_f32_16x16x32_bf16(qhi, bh8, sacc, 0, 0, 0);
#pragma unroll
      for (int reg = 0; reg < 4; ++reg) {
        float s = sacc[reg] + eb[msub][reg] * we + be;
        float e = __expf(s);
        rowsum[reg] += e;
        pbuf[wid][(lq * 4 + reg) * 68 + msub * 16 + lr] = split_bf_trunc_pack(e);
      }
    }

#pragma unroll
    for (int mw = 0; mw < 2; ++mw) {
      uint4 pa = *(uint4*)&pbuf[wid][lr * 68 + mw * 32 + lq * 8];
      uint4 pb = *(uint4*)&pbuf[wid][lr * 68 + mw * 32 + lq * 8 + 4];
      bf16x8 ahi, alo;
      unpack_u32x8(pa, pb, ahi, alo);
      {
        bf16x8 vh8 = *(bf16x8*)&vth[lr * 72 + mw * 32 + lq * 8];
        bf16x8 vl8 = *(bf16x8*)&vtl[lr * 72 + mw * 32 + lq * 8];
        O0 = __builtin_amdgcn_mfma_f32_16x16x32_bf16(alo, vh8, O0, 0, 0, 0);
        O0 = __builtin_amdgcn_mfma_f32_16x16x32_bf16(ahi, vl8, O0, 0, 0, 0);
        O0 = __builtin_amdgcn_mfma_f32_16x16x32_bf16(ahi, vh8, O0, 0, 0, 0);
      }
      {
        bf16x8 vh8 = *(bf16x8*)&vth[(16 + lr) * 72 + mw * 32 + lq * 8];
        bf16x8 vl8 = *(bf16x8*)&vtl[(16 + lr) * 72 + mw * 32 + lq * 8];
        O1 = __builtin_amdgcn_mfma_f32_16x16x32_bf16(alo, vh8, O1, 0, 0, 0);
        O1 = __builtin_amdgcn_mfma_f32_16x16x32_bf16(ahi, vl8, O1, 0, 0, 0);
        O1 = __builtin_amdgcn_mfma_f32_16x16x32_bf16(ahi, vh8, O1, 0, 0, 0);
      }
    }
  }

#pragma unroll
  for (int reg = 0; reg < 4; ++reg) {
#pragma unroll
    for (int off = 1; off < 16; off <<= 1)
      rowsum[reg] += __shfl_xor(rowsum[reg], off);
  }
  size_t pbase = (size_t)mh * BHND + bhb;
#pragma unroll
  for (int reg = 0; reg < 4; ++reg) {
    int n = nrow + reg;
    o_part[pbase + (size_t)n * Dn + lr] = O0[reg];
    o_part[pbase + (size_t)n * Dn + 16 + lr] = O1[reg];
    if (lr == 0)
      l_part[(size_t)mh * BHN + (size_t)(b * Hn + h) * Nn + n] = rowsum[reg];
  }
}

// ---------------- K4a': stats = 1/(l0+l1) ----------------
__global__ __launch_bounds__(256) void k_stats(const float* __restrict__ l_part,
                                               float* __restrict__ stats) {
  int i = blockIdx.x * 256 + threadIdx.x;
  stats[i] = 1.0f / (l_part[i] + l_part[BHN + i]);
}

// ---------------- K4b: edge output: recompute S, edge = sum_h wr*(p+s) + br ------
__global__ __launch_bounds__(256, 4) void k_edge_mfma(
    const short* __restrict__ q_hi, const short* __restrict__ q_lo,
    const short* __restrict__ k_hi, const short* __restrict__ k_lo,
    const float* __restrict__ eg, const float* __restrict__ stats,
    const float* __restrict__ w_expand, const float* __restrict__ b_expand,
    const float* __restrict__ w_reduce, const float* __restrict__ b_reduce,
    float* __restrict__ edge_out) {
  __shared__ short kh[64 * 40];
  __shared__ short kl[64 * 40];
  int blk = blockIdx.x;
  int mt = blk & 15;
  int nt = (blk >> 4) & 15;
  int b = blk >> 8;
  int n0 = nt * 64, m0 = mt * 64;
  int t = threadIdx.x, wid = t >> 6, l = t & 63;
  int lr = l & 15, lq = l >> 4;
  const float br = b_reduce[0];
  int nrow = n0 + wid * 16 + lq * 4;

  float eacc[4][4], ebias[4][4];
#pragma unroll
  for (int reg = 0; reg < 4; ++reg) {
    const float* ep = &eg[(size_t)(b * Nn + nrow + reg) * Nn + m0 + lr];
#pragma unroll
    for (int msub = 0; msub < 4; ++msub) {
      ebias[msub][reg] = ep[msub * 16];
      eacc[msub][reg] = br;
    }
  }

  for (int h = 0; h < Hn; ++h) {
    size_t bhb = (size_t)(b * Hn + h) * Nn * Dn;
    float we = w_expand[h], be = b_expand[h], wr = w_reduce[h];
    bf16x8 qhi, qlo;
    {
      size_t qoff = bhb + (size_t)(n0 + wid * 16 + lr) * Dn + lq * 8;
      qhi = *(const bf16x8*)&q_hi[qoff];
      qlo = *(const bf16x8*)&q_lo[qoff];
    }
    float invl[4];
#pragma unroll
    for (int reg = 0; reg < 4; ++reg)
      invl[reg] = stats[(size_t)(b * Hn + h) * Nn + nrow + reg];

    __syncthreads();
    {
      int row = t >> 2, c = (t & 3) * 8;
      *(uint4*)&kh[row * 40 + c] = *(const uint4*)&k_hi[bhb + (size_t)(m0 + row) * Dn + c];
      *(uint4*)&kl[row * 40 + c] = *(const uint4*)&k_lo[bhb + (size_t)(m0 + row) * Dn + c];
    }
    __syncthreads();
#pragma unroll
    for (int msub = 0; msub < 4; ++msub) {
      int mrow = msub * 16 + lr;
      bf16x8 bh8 = *(bf16x8*)&kh[mrow * 40 + lq * 8];
      bf16x8 bl8 = *(bf16x8*)&kl[mrow * 40 + lq * 8];
      f32x4 sacc = {0.f, 0.f, 0.f, 0.f};
      sacc = __builtin_amdgcn_mfma_f32_16x16x32_bf16(qlo, bh8, sacc, 0, 0, 0);
      sacc = __builtin_amdgcn_mfma_f32_16x16x32_bf16(qhi, bl8, sacc, 0, 0, 0);
      sacc = __builtin_amdgcn_mfma_f32_16x16x32_bf16(qhi, bh8, sacc, 0, 0, 0);
#pragma unroll
      for (int reg = 0; reg < 4; ++reg) {
        float s = sacc[reg] + ebias[msub][reg] * we + be;
        float p = __expf(s) * invl[reg];
        eacc[msub][reg] += wr * (p + s);
      }
    }
  }
#pragma unroll
  for (int msub = 0; msub < 4; ++msub)
#pragma unroll
    for (int reg = 0; reg < 4; ++reg)
      edge_out[(size_t)(b * Nn + nrow + reg) * Nn + m0 + msub * 16 + lr] = eacc[msub][reg];
}

// ---------------- K5: edge softmax + wsum ----------------
__global__ __launch_bounds__(256) void k_edge_soft(const float* __restrict__ edge,
                                                   float* __restrict__ wsum) {
  int bn = blockIdx.x;
  int t = threadIdx.x;
  const float* row = edge + (size_t)bn * Nn;
  float4 e = *(const float4*)&row[t * 4];
  float mx = fmaxf(fmaxf(e.x, e.y), fmaxf(e.z, e.w));
#pragma unroll
  for (int off = 32; off >= 1; off >>= 1) mx = fmaxf(mx, __shfl_xor(mx, off));
  __shared__ float sm[4], sl[4], sw[4];
  if ((t & 63) == 0) sm[t >> 6] = mx;
  __syncthreads();
  mx = fmaxf(fmaxf(sm[0], sm[1]), fmaxf(sm[2], sm[3]));
  float p0 = __expf(e.x - mx), p1 = __expf(e.y - mx), p2 = __expf(e.z - mx), p3 = __expf(e.w - mx);
  float ls = p0 + p1 + p2 + p3;
  float ws = p0 * e.x + p1 * e.y + p2 * e.z + p3 * e.w;
#pragma unroll
  for (int off = 32; off >= 1; off >>= 1) { ls += __shfl_xor(ls, off); ws += __shfl_xor(ws, off); }
  if ((t & 63) == 0) { sl[t >> 6] = ls; sw[t >> 6] = ws; }
  __syncthreads();
  if (t == 0) {
    float L = sl[0] + sl[1] + sl[2] + sl[3];
    float Wv = sw[0] + sw[1] + sw[2] + sw[3];
    wsum[bn] = Wv / L;
  }
}

// ---------------- K6: ((o0+o1)*invl + wsum*w_fc + b_fc) @ w_proj + b_proj ----------
__global__ __launch_bounds__(256) void k_proj_gemm(const float* __restrict__ o_part,
                                                   const float* __restrict__ stats,
                                                   const float* __restrict__ wsum,
                                                   const float* __restrict__ wfc,
                                                   const float* __restrict__ bfc,
                                                   const float* __restrict__ wproj,
                                                   const float* __restrict__ bproj,
                                                   float* __restrict__ out) {
  __shared__ __align__(16) float at[16][68];
  __shared__ __align__(16) float bt[16][68];
  __shared__ float ct[64][65];
  int m0 = blockIdx.x * 64;
  int j0 = blockIdx.y * 64;
  int t = threadIdx.x;
  int tx = t & 15, ty = t >> 4;
  float4 acc[4] = {};
  for (int k0 = 0; k0 < 256; k0 += 16) {
    {
      int row = t >> 2, k4 = (t & 3) << 2;
      int m = m0 + row;
      int bb = m >> 10, n = m & 1023;
      int c = k0 + k4;
      int h = c >> 5, dd = c & 31;
      float wsm = wsum[m];
      size_t ob = ((size_t)(bb * Hn + h) * Nn + n) * Dn + dd;
      float4 oa = *(const float4*)&o_part[ob];
      float4 oc = *(const float4*)&o_part[BHND + ob];
      float inv = stats[(size_t)(bb * Hn + h) * Nn + n];
      float4 a;
      a.x = (oa.x + oc.x) * inv + wsm * wfc[c + 0] + bfc[c + 0];
      a.y = (oa.y + oc.y) * inv + wsm * wfc[c + 1] + bfc[c + 1];
      a.z = (oa.z + oc.z) * inv + wsm * wfc[c + 2] + bfc[c + 2];
      a.w = (oa.w + oc.w) * inv + wsm * wfc[c + 3] + bfc[c + 3];
      at[k4 + 0][row] = a.x; at[k4 + 1][row] = a.y;
      at[k4 + 2][row] = a.z; at[k4 + 3][row] = a.w;
      int rb = t >> 4, jb = (t & 15) << 2;
      *(float4*)&bt[rb][jb] = *(const float4*)&wproj[(size_t)(k0 + rb) * 256 + j0 + jb];
    }
    __syncthreads();
#pragma unroll
    for (int kk = 0; kk < 16; ++kk) {
      float4 a4 = *(float4*)&at[kk][ty << 2];
      float4 b4 = *(float4*)&bt[kk][tx << 2];
      acc[0].x += a4.x * b4.x; acc[0].y += a4.x * b4.y; acc[0].z += a4.x * b4.z; acc[0].w += a4.x * b4.w;
      acc[1].x += a4.y * b4.x; acc[1].y += a4.y * b4.y; acc[1].z += a4.y * b4.z; acc[1].w += a4.y * b4.w;
      acc[2].x += a4.z * b4.x; acc[2].y += a4.z * b4.y; acc[2].z += a4.z * b4.z; acc[2].w += a4.z * b4.w;
      acc[3].x += a4.w * b4.x; acc[3].y += a4.w * b4.y; acc[3].z += a4.w * b4.z; acc[3].w += a4.w * b4.w;
    }
    __syncthreads();
  }
#pragma unroll
  for (int i = 0; i < 4; ++i) {
    ct[(ty << 2) + i][(tx << 2) + 0] = acc[i].x + bproj[j0 + (tx << 2) + 0];
    ct[(ty << 2) + i][(tx << 2) + 1] = acc[i].y + bproj[j0 + (tx << 2) + 1];
    ct[(ty << 2) + i][(tx << 2) + 2] = acc[i].z + bproj[j0 + (tx << 2) + 2];
    ct[(ty << 2) + i][(tx << 2) + 3] = acc[i].w + bproj[j0 + (tx << 2) + 3];
  }
  __syncthreads();
  int b = m0 >> 10, n0 = m0 & 1023;
  int n4 = t & 15, c0i = t >> 4;
#pragma unroll
  for (int u = 0; u < 4; ++u) {
    int ci = c0i + u * 16;
    float4 val = { ct[(n4 << 2) + 0][ci], ct[(n4 << 2) + 1][ci],
                   ct[(n4 << 2) + 2][ci], ct[(n4 << 2) + 3][ci] };
    *(float4*)&out[(size_t)(b * Cn + j0 + ci) * Nn + n0 + (n4 << 2)] = val;
  }
}

// ---------------- launch ----------------
extern "C" void kernel_launch(void* const* d_in, const int* in_sizes, int n_in,
                              void* d_out, int out_size, void* d_ws, size_t ws_size,
                              hipStream_t stream) {
  (void)in_sizes; (void)n_in; (void)out_size; (void)ws_size;
  const float* node_embeds = (const float*)d_in[0];
  const float* edge_embeds = (const float*)d_in[1];
  const float* da_prior    = (const float*)d_in[2];
  const float* gamma       = (const float*)d_in[3];
  const float* beta        = (const float*)d_in[4];
  const float* w_qkv       = (const float*)d_in[5];
  const float* w_proj      = (const float*)d_in[6];
  const float* b_proj      = (const float*)d_in[7];
  const float* w_expand    = (const float*)d_in[8];
  const float* b_expand    = (const float*)d_in[9];
  const float* w_reduce    = (const float*)d_in[10];
  const float* b_reduce    = (const float*)d_in[11];
  const float* w_fc        = (const float*)d_in[12];
  const float* b_fc        = (const float*)d_in[13];
  float* out_node = (float*)d_out;
  float* out_edge = out_node + (size_t)Bn * Cn * Nn;

  const size_t M = 1048576;  // B*N*C elements
  float* W = (float*)d_ws;
  // [0, M):   x-transposed (dead after prep_ln) -> o_part half 0
  // [M, 2M):  ln (dead after qkv)               -> o_part half 1
  // [2M, 3M): V^T bf16 planes (qkv epilogue writes; attn_core reads)
  // [3M, 5M): q/k bf16 hi/lo planes
  float* ws_x   = W;
  float* ws_ln  = W + M;
  float* o_part = W;                     // [2][B,H,N,D] overlays x/ln after death
  short* vt_hi  = (short*)(W + 2 * M);
  short* vt_lo  = vt_hi + M;
  short* q_hi   = (short*)(W + 3 * M);
  short* q_lo   = q_hi + M;
  short* k_hi   = q_hi + 2 * M;
  short* k_lo   = q_hi + 3 * M;
  float* ws_pp    = W + 5 * M;
  float* ws_prior = ws_pp + Bn * 32 * Cn;
  float* ws_wsum  = ws_prior + Bn * Cn;
  float* ws_stats = ws_wsum + Bn * Nn;          // [B,H,N]
  float* l_part   = ws_stats + BHN;             // [2][B,H,N]

  k_prior_part<<<dim3(Bn * 32), dim3(256), 0, stream>>>(da_prior, ws_pp);
  k_prior_red<<<dim3(Bn), dim3(256), 0, stream>>>(ws_pp, ws_prior);
  k_transpose<<<dim3(Bn * 256), dim3(256), 0, stream>>>(node_embeds, ws_x);
  k_prep_ln<<<dim3(Bn * Nn), dim3(256), 0, stream>>>(ws_x, edge_embeds, ws_prior,
                                                     gamma, beta, ws_ln);
  k_qkv_gemm<<<dim3(64, 12), dim3(256), 0, stream>>>(ws_ln, w_qkv, q_hi, q_lo,
                                                     k_hi, k_lo, vt_hi, vt_lo);
  k_attn_core<<<dim3(Bn * Hn * 16 * 2), dim3(256), 0, stream>>>(
      q_hi, q_lo, k_hi, k_lo, vt_hi, vt_lo, edge_embeds, w_expand, b_expand,
      o_part, l_part);
  k_stats<<<dim3(BHN / 256), dim3(256), 0, stream>>>(l_part, ws_stats);
  k_edge_mfma<<<dim3(Bn * 16 * 16), dim3(256), 0, stream>>>(
      q_hi, q_lo, k_hi, k_lo, edge_embeds, ws_stats, w_expand, b_expand,
      w_reduce, b_reduce, out_edge);
  k_edge_soft<<<dim3(Bn * Nn), dim3(256), 0, stream>>>(out_edge, ws_wsum);
  k_proj_gemm<<<dim3(64, 4), dim3(256), 0, stream>>>(o_part, ws_stats, ws_wsum,
                                                     w_fc, b_fc, w_proj, b_proj,
                                                     out_node);
}